// Round 3
// baseline (1337.940 us; speedup 1.0000x reference)
//
#include <hip/hip_runtime.h>
#include <cstdint>
#include <cmath>

using u16 = unsigned short;

typedef __bf16 bf16x8 __attribute__((ext_vector_type(8)));
typedef float  f32x4  __attribute__((ext_vector_type(4)));

__device__ __forceinline__ float b2f(u16 u) {
    return __uint_as_float(((unsigned int)u) << 16);
}
__device__ __forceinline__ u16 f2b(float f) {
    unsigned int x = __float_as_uint(f);
    unsigned int r = (x + 0x7fffu + ((x >> 16) & 1u)) >> 16;
    return (u16)r;
}

// async global->LDS, 16B per lane; LDS dest is wave-uniform base + lane*16.
__device__ __forceinline__ void gload16(const u16* g, u16* l) {
    __builtin_amdgcn_global_load_lds((__attribute__((address_space(1))) void*)g,
                                     (__attribute__((address_space(3))) void*)l,
                                     16, 0, 0);
}

// wave-local LDS RAW fence: drain ds ops, pin scheduling (rule #18).
#define LGKM0_FENCE() do { \
    asm volatile("s_waitcnt lgkmcnt(0)" ::: "memory"); \
    __builtin_amdgcn_sched_barrier(0); } while (0)

// exact-enough gelu: erf via Abramowitz-Stegun 7.1.26 (|err| <= 1.5e-7).
__device__ __forceinline__ float gelu_f(float x) {
    float z = fabsf(x) * 0.70710678118f;
    float t = __builtin_amdgcn_rcpf(fmaf(0.3275911f, z, 1.0f));
    float poly = fmaf(fmaf(fmaf(fmaf(1.061405429f, t, -1.453152027f),
                               t, 1.421413741f),
                          t, -0.284496736f),
                     t, 0.254829592f) * t;
    float e = __expf(-z * z);
    float erfv = copysignf(1.0f - poly * e, x);
    return 0.5f * x * (1.0f + erfv);
}

// token permutation: original (b, hw) -> window-gathered index t'
__device__ __forceinline__ int tprime(int b, int hw) {
    int r = hw / 112, c = hw - r * 112;
    int wy = r / 7, iy = r - wy * 7;
    int wx = c / 7, ix = c - wx * 7;
    return (b * 256 + wy * 16 + wx) * 49 + iy * 7 + ix;
}

// ---------------------------------------------------------------------------
// Input dtype detection: f32 N(0,1) data has exponent field in ~[117,130];
// bf16 pairs read as f32 decode to exponents ~250+. Writes 1 if f32.
__global__ void detect_dtype(const unsigned int* __restrict__ x, int* __restrict__ flag) {
    __shared__ int cnt[256];
    int tid = threadIdx.x;
    int c = 0;
#pragma unroll
    for (int i = 0; i < 16; ++i) {
        unsigned int w = x[tid * 16 + i];
        int e = (w >> 23) & 0xFF;
        if (e >= 100 && e <= 150) ++c;
    }
    cnt[tid] = c;
    __syncthreads();
    if (tid == 0) {
        int s = 0;
        for (int i = 0; i < 256; ++i) s += cnt[i];
        flag[0] = (s > 3072) ? 1 : 0;
    }
}

// Convert any input tensor to canonical bf16 (copy if already bf16).
__global__ void convertk(const void* __restrict__ src, u16* __restrict__ dst, int n,
                         const int* __restrict__ flagp) {
    int isf = flagp[0];
    int i = blockIdx.x * 256 + threadIdx.x;
    if (i < n) dst[i] = isf ? f2b(((const float*)src)[i]) : ((const u16*)src)[i];
}

// ---------------------------------------------------------------------------
// Weight transpose: in (K,N) bf16 -> out (N,K).  grid (N/32, K/32), block 256.
__global__ void wtrans(const u16* __restrict__ in, u16* __restrict__ out, int K, int N) {
    __shared__ u16 tile[32][33];
    int n0 = blockIdx.x * 32, k0 = blockIdx.y * 32;
    int tx = threadIdx.x & 31, ty = threadIdx.x >> 5;  // 32 x 8
#pragma unroll
    for (int i = 0; i < 4; ++i)
        tile[ty + i * 8][tx] = in[(size_t)(k0 + ty + i * 8) * N + n0 + tx];
    __syncthreads();
#pragma unroll
    for (int i = 0; i < 4; ++i)
        out[(size_t)(n0 + ty + i * 8) * K + k0 + tx] = tile[tx][ty + i * 8];
}

// ---------------------------------------------------------------------------
// LN1 stats over C for x in (B,C,HW), dtype per flag. One thread per token.
__global__ void ln1_stats(const void* __restrict__ x, float* __restrict__ mean,
                          float* __restrict__ rstd, const int* __restrict__ flagp) {
    int isf = flagp[0];
    int t = blockIdx.x * 256 + threadIdx.x;      // < 100352
    int b = t / 12544, hw = t - b * 12544;
    size_t base = (size_t)b * 384 * 12544 + hw;
    float s = 0.f, sq = 0.f;
    if (isf) {
        const float* p = (const float*)x + base;
        for (int c = 0; c < 384; ++c) {
            float v = p[(size_t)c * 12544];
            s += v; sq += v * v;
        }
    } else {
        const u16* p = (const u16*)x + base;
        for (int c = 0; c < 384; ++c) {
            float v = b2f(p[(size_t)c * 12544]);
            s += v; sq += v * v;
        }
    }
    float m = s * (1.0f / 384.0f);
    float var = sq * (1.0f / 384.0f) - m * m;
    mean[t] = m;
    rstd[t] = rsqrtf(var + 1e-5f);
}

// Transpose + normalize: x(B,C,HW) -> xt(T',C) raw bf16, xn(T',C) normalized
// bf16 — rows written in window-gathered t' order.
// grid (HW/64=196, C/64=6, B=8), block 256.
__global__ void ln1_apply(const void* __restrict__ x, const float* __restrict__ mean,
                          const float* __restrict__ rstd, const u16* __restrict__ g1,
                          const u16* __restrict__ b1, u16* __restrict__ xt,
                          u16* __restrict__ xn, const int* __restrict__ flagp) {
    __shared__ float tile[64][65];
    int isf = flagp[0];
    int hw0 = blockIdx.x * 64, c0 = blockIdx.y * 64, b = blockIdx.z;
    int tid = threadIdx.x;
    {
        int hl = tid & 63, cq = tid >> 6;
        size_t base = ((size_t)b * 384 + c0) * 12544 + hw0;
#pragma unroll
        for (int it = 0; it < 16; ++it) {
            int cl = cq * 16 + it;
            size_t idx = base + (size_t)cl * 12544 + hl;
            tile[cl][hl] = isf ? ((const float*)x)[idx] : b2f(((const u16*)x)[idx]);
        }
    }
    __syncthreads();
    {
        int cl = tid & 63, hq = tid >> 6;
        float g = b2f(g1[c0 + cl]), bb = b2f(b1[c0 + cl]);
#pragma unroll
        for (int it = 0; it < 16; ++it) {
            int hl = hq * 16 + it;
            int hw = hw0 + hl;
            int t = b * 12544 + hw;                 // original order (stats)
            int tp = tprime(b, hw);                 // window-gathered order
            float v = tile[cl][hl];
            size_t o = (size_t)tp * 384 + c0 + cl;
            xt[o] = f2b(v);
            xn[o] = f2b((v - mean[t]) * rstd[t] * g + bb);
        }
    }
}

// ---------------------------------------------------------------------------
// bf16 GEMM: C = A(MxK) * Bt(NxK)^T + bias.
// Double-buffered global_load_lds staging, ONE barrier per K-step (loads for
// step t+1 overlap MFMA of step t). 128x128 tile, BK=32. XCD-aware bijective
// block swizzle. Conflict-free LDS-staged f32 epilogue (stride 132) with
// coalesced 16B stores. EPI 0: bias. 1: bias+gelu. 2: bias+res add.
template <int EPI>
__global__ void gemm_bt(const u16* __restrict__ A, const u16* __restrict__ Bt,
                        const u16* __restrict__ bias, const u16* __restrict__ res,
                        u16* __restrict__ Cout, int M, int N, int K) {
    __shared__ __align__(16) u16 S[2][2][128 * 32];   // [buf][A/B], 32 KB total
    const int tid = threadIdx.x;
    const int wave = tid >> 6, lane = tid & 63;

    // XCD-aware bijective swizzle of flattened block id (8 XCDs)
    const int nbx = gridDim.x;
    const int nwg = nbx * gridDim.y;
    int flat = blockIdx.y * nbx + blockIdx.x;
    {
        int q = nwg >> 3, r = nwg & 7;
        int xcd = flat & 7, loc = flat >> 3;
        flat = (xcd < r ? xcd * (q + 1) : r * (q + 1) + (xcd - r) * q) + loc;
    }
    const int m0 = (flat / nbx) * 128, n0 = (flat % nbx) * 128;

    const int wm = wave & 1, wn = wave >> 1;
    const int m15 = lane & 15, q4 = lane >> 4;

    // staging: lane i -> row (i>>2), col (i&3)*8 — linear base+lane*16B in LDS.
    const u16* gA = A + (size_t)(m0 + wave * 32 + (lane >> 2)) * K + (lane & 3) * 8;
    const u16* gB = Bt + (size_t)(n0 + wave * 32 + (lane >> 2)) * K + (lane & 3) * 8;

    f32x4 acc[4][4];
#pragma unroll
    for (int i = 0; i < 4; ++i)
#pragma unroll
        for (int j = 0; j < 4; ++j) acc[i][j] = {0.f, 0.f, 0.f, 0.f};

    const int nt = K >> 5;
    // prologue: stage tile 0 into buffer 0
    {
        u16* lA = &S[0][0][(wave * 32) * 32];
        u16* lB = &S[0][1][(wave * 32) * 32];
        gload16(gA, lA);
        gload16(gA + 16 * (size_t)K, lA + 16 * 32);
        gload16(gB, lB);
        gload16(gB + 16 * (size_t)K, lB + 16 * 32);
    }
    __syncthreads();   // drains vmcnt(0): tile 0 visible

    for (int t = 0; t < nt; ++t) {
        const int cur = t & 1;
        if (t + 1 < nt) {   // stage next tile into other buffer (overlaps MFMA)
            const int k0 = (t + 1) << 5;
            u16* lA = &S[cur ^ 1][0][(wave * 32) * 32];
            u16* lB = &S[cur ^ 1][1][(wave * 32) * 32];
            gload16(gA + k0, lA);
            gload16(gA + k0 + 16 * (size_t)K, lA + 16 * 32);
            gload16(gB + k0, lB);
            gload16(gB + k0 + 16 * (size_t)K, lB + 16 * 32);
        }
        bf16x8 af[4], bfr[4];
#pragma unroll
        for (int i = 0; i < 4; ++i)
            af[i] = *(const bf16x8*)&S[cur][0][(wm * 64 + i * 16 + m15) * 32 + q4 * 8];
#pragma unroll
        for (int j = 0; j < 4; ++j)
            bfr[j] = *(const bf16x8*)&S[cur][1][(wn * 64 + j * 16 + m15) * 32 + q4 * 8];
#pragma unroll
        for (int i = 0; i < 4; ++i)
#pragma unroll
            for (int j = 0; j < 4; ++j)
                acc[i][j] = __builtin_amdgcn_mfma_f32_16x16x32_bf16(af[i], bfr[j],
                                                                    acc[i][j], 0, 0, 0);
        __syncthreads();  // drains next-tile loads; guards WAR for buffer reuse
    }

    // Epilogue: 4 passes of 32 rows through a 32x132-stride f32 LDS tile.
    constexpr int CSTR = 132;   // +4 pad: bank shift 4/row -> conflict-free
    float* Cs = (float*)&S[0][0][0];   // 32*132*4 = 16.9 KB (fits in 32 KB)
#pragma unroll
    for (int p = 0; p < 4; ++p) {
        __syncthreads();  // Cs free (main-loop reads / prev pass reads done)
        if (wm == (p >> 1)) {
            const int ibase = (p & 1) * 2;
#pragma unroll
            for (int jj = 0; jj < 4; ++jj) {
                int n = n0 + wn * 64 + jj * 16 + m15;
                float bv = b2f(bias[n]);
#pragma unroll
                for (int ii = 0; ii < 2; ++ii) {
                    int i = ibase + ii;
#pragma unroll
                    for (int r = 0; r < 4; ++r) {
                        float v = acc[i][jj][r] + bv;
                        if (EPI == 1) v = gelu_f(v);
                        Cs[(ii * 16 + q4 * 4 + r) * CSTR + wn * 64 + jj * 16 + m15] = v;
                    }
                }
            }
        }
        __syncthreads();  // staged values visible
#pragma unroll
        for (int it = 0; it < 2; ++it) {
            int r2 = it * 16 + (tid >> 4);
            int c8 = (tid & 15) * 8;
            size_t goff = (size_t)(m0 + p * 32 + r2) * N + n0 + c8;
            f32x4 v0 = *(const f32x4*)&Cs[r2 * CSTR + c8];
            f32x4 v1 = *(const f32x4*)&Cs[r2 * CSTR + c8 + 4];
            uint4 rv = {0u, 0u, 0u, 0u};
            const u16* rp = (const u16*)&rv;
            if (EPI == 2) rv = *(const uint4*)&res[goff];
            u16 outv[8];
#pragma unroll
            for (int e = 0; e < 4; ++e) {
                float a = v0[e];
                if (EPI == 2) a += b2f(rp[e]);
                outv[e] = f2b(a);
                float bq = v1[e];
                if (EPI == 2) bq += b2f(rp[4 + e]);
                outv[4 + e] = f2b(bq);
            }
            *(uint4*)&Cout[goff] = *(const uint4*)outv;
        }
    }
}

// ---------------------------------------------------------------------------
// Window attention, window-gathered token order, BARRIER-FREE: each wave is
// fully independent (private 8 KB LDS region), Q/K fragments loaded directly
// from global (fragment layout == 16 rows x 64B lines per instruction), V
// transposed through LDS, P through LDS, output staged in LDS for full-line
// coalesced 16B stores. One block per window (2048), 4 waves; wave w does
// heads w, w+4, w+8. Region reuse relies on in-order per-wave DS execution.
__global__ __launch_bounds__(256, 4)
void attn_win(const u16* __restrict__ qkv, const u16* __restrict__ rpb,
              u16* __restrict__ outp) {
    __shared__ __align__(16) u16 lds[4][4096];   // 8 KB per wave
    const int tid = threadIdx.x;
    const int wave = tid >> 6, lane = tid & 63;
    const int t0p = blockIdx.x * 49;
    u16* Vt = &lds[wave][0];   // [0,4096)B: Vt[d][n], 32x64
    u16* Ps = &lds[wave][0];   // [0,8192)B: P[row][col], 64x64 (after vf read)
    u16* Po = &lds[wave][0];   // [0,5120)B: out stage, stride 40 (after pf read)
    const int m15 = lane & 15, q4 = lane >> 4;
    const int rr = lane >> 2, dq = lane & 3;
    const float scale = 0.17677669529663687f;  // 1/sqrt(32)

    for (int hl = 0; hl < 3; ++hl) {
        const int h = hl * 4 + wave;
        const u16* qbase = qkv + (size_t)t0p * 1152 + h * 32;
        // --- Q/K fragments straight from global (rows >=49 clamp to 48) ---
        bf16x8 qf[4], kf[4];
#pragma unroll
        for (int i = 0; i < 4; ++i) {
            int row = i * 16 + m15;
            int rc = row < 49 ? row : 48;
            const u16* g = qbase + (size_t)rc * 1152 + q4 * 8;
            qf[i] = *(const bf16x8*)g;
            kf[i] = *(const bf16x8*)(g + 384);
        }
        // --- V rows -> LDS transpose (in-order DS; overwrites prev iter) ---
#pragma unroll
        for (int p = 0; p < 4; ++p) {
            int n = p * 16 + rr;
            uint4 vv = {0u, 0u, 0u, 0u};
            if (n < 49)
                vv = *(const uint4*)(qbase + (size_t)n * 1152 + 768 + dq * 8);
            const u16* pv = (const u16*)&vv;
#pragma unroll
            for (int ii = 0; ii < 8; ++ii) Vt[(dq * 8 + ii) * 64 + n] = pv[ii];
        }
        LGKM0_FENCE();   // Vt writes drained before vf reads
        bf16x8 vf[2][2];
#pragma unroll
        for (int j = 0; j < 2; ++j)
#pragma unroll
            for (int kk = 0; kk < 2; ++kk)
                vf[j][kk] = *(const bf16x8*)&Vt[(j * 16 + m15) * 64 + kk * 32 + q4 * 8];
        // --- QK^T ---
        f32x4 sc[4][4];
#pragma unroll
        for (int i = 0; i < 4; ++i)
#pragma unroll
            for (int j = 0; j < 4; ++j) {
                sc[i][j] = {0.f, 0.f, 0.f, 0.f};
                sc[i][j] = __builtin_amdgcn_mfma_f32_16x16x32_bf16(qf[i], kf[j],
                                                                   sc[i][j], 0, 0, 0);
            }
#pragma unroll
        for (int i = 0; i < 4; ++i) {
#pragma unroll
            for (int r = 0; r < 4; ++r) {
                int row = i * 16 + q4 * 4 + r;
                int rc = row < 49 ? row : 48;
                int ri = rc / 7, rj = rc - ri * 7;
#pragma unroll
                for (int j = 0; j < 4; ++j) {
                    int col = j * 16 + m15;
                    int cc = col < 49 ? col : 48;
                    int mi = cc / 7, mj = cc - mi * 7;
                    int idx = ((ri - mi + 6) * 13 + (rj - mj + 6)) * 12 + h;
                    float bias = b2f(rpb[idx]);
                    float s = sc[i][j][r] * scale + bias;
                    sc[i][j][r] = (row < 49 && col < 49) ? s : -1e30f;
                }
            }
        }
        // --- softmax over 64 cols (4 regs x 16 lanes) ---
#pragma unroll
        for (int i = 0; i < 4; ++i) {
#pragma unroll
            for (int r = 0; r < 4; ++r) {
                float mx = fmaxf(fmaxf(sc[i][0][r], sc[i][1][r]),
                                 fmaxf(sc[i][2][r], sc[i][3][r]));
                mx = fmaxf(mx, __shfl_xor(mx, 1));
                mx = fmaxf(mx, __shfl_xor(mx, 2));
                mx = fmaxf(mx, __shfl_xor(mx, 4));
                mx = fmaxf(mx, __shfl_xor(mx, 8));
                float e0 = __expf(sc[i][0][r] - mx);
                float e1 = __expf(sc[i][1][r] - mx);
                float e2 = __expf(sc[i][2][r] - mx);
                float e3 = __expf(sc[i][3][r] - mx);
                float sum = e0 + e1 + e2 + e3;
                sum += __shfl_xor(sum, 1);
                sum += __shfl_xor(sum, 2);
                sum += __shfl_xor(sum, 4);
                sum += __shfl_xor(sum, 8);
                float inv = 1.0f / sum;
                sc[i][0][r] = e0 * inv;
                sc[i][1][r] = e1 * inv;
                sc[i][2][r] = e2 * inv;
                sc[i][3][r] = e3 * inv;
            }
        }
        // --- P -> LDS (layout change); vf already in registers ---
#pragma unroll
        for (int i = 0; i < 4; ++i)
#pragma unroll
            for (int r = 0; r < 4; ++r)
#pragma unroll
                for (int j = 0; j < 4; ++j)
                    Ps[(i * 16 + q4 * 4 + r) * 64 + j * 16 + m15] = f2b(sc[i][j][r]);
        LGKM0_FENCE();   // P writes drained before pf reads
        // --- PV ---
        f32x4 oacc[4][2];
#pragma unroll
        for (int i = 0; i < 4; ++i)
#pragma unroll
            for (int j = 0; j < 2; ++j) oacc[i][j] = {0.f, 0.f, 0.f, 0.f};
#pragma unroll
        for (int i = 0; i < 4; ++i) {
#pragma unroll
            for (int kk = 0; kk < 2; ++kk) {
                bf16x8 pf = *(const bf16x8*)&Ps[(i * 16 + m15) * 64 + kk * 32 + q4 * 8];
#pragma unroll
                for (int j = 0; j < 2; ++j)
                    oacc[i][j] = __builtin_amdgcn_mfma_f32_16x16x32_bf16(pf, vf[j][kk],
                                                                         oacc[i][j], 0, 0, 0);
            }
        }
        // --- stage output tile (49x32) in LDS, stride 40 u16 (80B, 16-align) ---
#pragma unroll
        for (int i = 0; i < 4; ++i)
#pragma unroll
            for (int r = 0; r < 4; ++r) {
                int row = i * 16 + q4 * 4 + r;
#pragma unroll
                for (int j = 0; j < 2; ++j)
                    Po[row * 40 + j * 16 + m15] = f2b(oacc[i][j][r]);
            }
        LGKM0_FENCE();   // Po writes drained before coalesced read-out
        // --- full-line coalesced store: 4 lanes x 16B = 64B per row ---
#pragma unroll
        for (int w2 = 0; w2 < 4; ++w2) {
            int row = w2 * 16 + rr;
            if (row < 49) {
                uint4 ov = *(const uint4*)&Po[row * 40 + dq * 8];
                *(uint4*)&outp[(size_t)(t0p + row) * 384 + h * 32 + dq * 8] = ov;
            }
        }
    }
}

// ---------------------------------------------------------------------------
// LN2: y(T,384) bf16 -> out(T,384) bf16. One wave per token.
__global__ void ln2_kernel(const u16* __restrict__ y, const u16* __restrict__ g2,
                           const u16* __restrict__ b2, u16* __restrict__ out) {
    int wave = threadIdx.x >> 6, lane = threadIdx.x & 63;
    size_t t = (size_t)blockIdx.x * 4 + wave;
    const u16* row = y + t * 384;
    float v[6];
    float s = 0.f, sq = 0.f;
#pragma unroll
    for (int i = 0; i < 6; ++i) {
        v[i] = b2f(row[lane + i * 64]);
        s += v[i]; sq += v[i] * v[i];
    }
#pragma unroll
    for (int m = 1; m < 64; m <<= 1) {
        s += __shfl_xor(s, m);
        sq += __shfl_xor(sq, m);
    }
    float mean = s * (1.0f / 384.0f);
    float var = sq * (1.0f / 384.0f) - mean * mean;
    float rstd = rsqrtf(var + 1e-5f);
#pragma unroll
    for (int i = 0; i < 6; ++i) {
        int c = lane + i * 64;
        out[t * 384 + c] = f2b((v[i] - mean) * rstd * b2f(g2[c]) + b2f(b2[c]));
    }
}

// ---------------------------------------------------------------------------
// final (T',384) bf16 (window-gathered rows) -> out (B,384,112,112).
// grid (196,6,8), block 256.
__global__ void out_transpose(const u16* __restrict__ fin, void* __restrict__ out,
                              const int* __restrict__ flagp) {
    __shared__ float tile[64][65];
    int isf = flagp[0];
    int hw0 = blockIdx.x * 64, c0 = blockIdx.y * 64, b = blockIdx.z;
    int tid = threadIdx.x;
    {
        int cl = tid & 63, hq = tid >> 6;
#pragma unroll
        for (int it = 0; it < 16; ++it) {
            int hl = hq * 16 + it;
            int tp = tprime(b, hw0 + hl);
            tile[hl][cl] = b2f(fin[(size_t)tp * 384 + c0 + cl]);
        }
    }
    __syncthreads();
    {
        int hl = tid & 63, cq = tid >> 6;
#pragma unroll
        for (int it = 0; it < 16; ++it) {
            int cl = cq * 16 + it;
            size_t o = ((size_t)b * 384 + c0 + cl) * 12544 + hw0 + hl;
            float v = tile[hl][cl];
            if (isf) ((float*)out)[o] = v;
            else     ((u16*)out)[o] = f2b(v);
        }
    }
}

// ---------------------------------------------------------------------------
extern "C" void kernel_launch(void* const* d_in, const int* in_sizes, int n_in,
                              void* d_out, int out_size, void* d_ws, size_t ws_size,
                              hipStream_t stream) {
    constexpr int T = 100352, C = 384, HID = 1536, NQ = 1152;
    const void* x      = d_in[0];
    u16* out_any = (u16*)d_out;  // dtype resolved device-side
    (void)out_any;

    char* ws = (char*)d_ws;
    size_t off = 0;
    auto alloc = [&](size_t bytes) { char* p = ws + off; off += (bytes + 255) & ~(size_t)255; return p; };
    int*   flag   = (int*)alloc(4);
    // canonical bf16 copies of all non-x inputs
    u16* cw_qkv  = (u16*)alloc((size_t)C * NQ * 2);
    u16* cb_qkv  = (u16*)alloc((size_t)NQ * 2);
    u16* crpb    = (u16*)alloc((size_t)169 * 12 * 2);
    u16* cw_proj = (u16*)alloc((size_t)C * C * 2);
    u16* cb_proj = (u16*)alloc((size_t)C * 2);
    u16* cg1     = (u16*)alloc((size_t)C * 2);
    u16* cb1     = (u16*)alloc((size_t)C * 2);
    u16* cg2     = (u16*)alloc((size_t)C * 2);
    u16* cb2     = (u16*)alloc((size_t)C * 2);
    u16* cw_fc1  = (u16*)alloc((size_t)C * HID * 2);
    u16* cb_fc1  = (u16*)alloc((size_t)HID * 2);
    u16* cw_fc2  = (u16*)alloc((size_t)HID * C * 2);
    u16* cb_fc2  = (u16*)alloc((size_t)C * 2);
    // transposed weights
    u16* wqkvT  = (u16*)alloc((size_t)C * NQ * 2);
    u16* wprojT = (u16*)alloc((size_t)C * C * 2);
    u16* wfc1T  = (u16*)alloc((size_t)C * HID * 2);
    u16* wfc2T  = (u16*)alloc((size_t)HID * C * 2);
    // activations (all token-major buffers in window-gathered t' order)
    u16*   xt     = (u16*)alloc((size_t)T * C * 2);
    u16*   bufB   = (u16*)alloc((size_t)T * C * 2);    // xn -> attnout -> h_in -> final
    u16*   bufC   = (u16*)alloc((size_t)T * HID * 2);  // qkv -> hid
    u16*   ybuf   = (u16*)alloc((size_t)T * C * 2);
    float* meanb  = (float*)alloc((size_t)T * 4);
    float* rstdb  = (float*)alloc((size_t)T * 4);

    // 1) detect input dtype from x
    detect_dtype<<<1, 256, 0, stream>>>((const unsigned int*)x, flag);

    // 2) canonicalize all non-x inputs to bf16
    auto conv = [&](const void* src, u16* dst, int n) {
        convertk<<<(n + 255) / 256, 256, 0, stream>>>(src, dst, n, flag);
    };
    conv(d_in[1], cg1, C);
    conv(d_in[2], cb1, C);
    conv(d_in[3], cw_qkv, C * NQ);
    conv(d_in[4], cb_qkv, NQ);
    conv(d_in[5], crpb, 169 * 12);
    conv(d_in[6], cw_proj, C * C);
    conv(d_in[7], cb_proj, C);
    conv(d_in[8], cg2, C);
    conv(d_in[9], cb2, C);
    conv(d_in[10], cw_fc1, C * HID);
    conv(d_in[11], cb_fc1, HID);
    conv(d_in[12], cw_fc2, HID * C);
    conv(d_in[13], cb_fc2, C);

    // 3) weight transposes (B^T layout for GEMM)
    wtrans<<<dim3(NQ / 32, C / 32), 256, 0, stream>>>(cw_qkv, wqkvT, C, NQ);
    wtrans<<<dim3(C / 32, C / 32), 256, 0, stream>>>(cw_proj, wprojT, C, C);
    wtrans<<<dim3(HID / 32, C / 32), 256, 0, stream>>>(cw_fc1, wfc1T, C, HID);
    wtrans<<<dim3(C / 32, HID / 32), 256, 0, stream>>>(cw_fc2, wfc2T, HID, C);

    // 4) LN1 + transpose (outputs in window-gathered t' order)
    ln1_stats<<<T / 256, 256, 0, stream>>>(x, meanb, rstdb, flag);
    ln1_apply<<<dim3(196, 6, 8), 256, 0, stream>>>(x, meanb, rstdb, cg1, cb1, xt, bufB, flag);

    // 5) QKV
    gemm_bt<0><<<dim3(NQ / 128, T / 128), 256, 0, stream>>>(bufB, wqkvT, cb_qkv, nullptr,
                                                            bufC, T, NQ, C);
    // 6) attention (qkv in bufC -> attnout in bufB), dense per-window rows
    attn_win<<<2048, 256, 0, stream>>>(bufC, crpb, bufB);

    // 7) proj + residual(xt) -> y
    gemm_bt<2><<<dim3(C / 128, T / 128), 256, 0, stream>>>(bufB, wprojT, cb_proj, xt,
                                                           ybuf, T, C, C);
    // 8) LN2 -> bufB
    ln2_kernel<<<T / 4, 256, 0, stream>>>(ybuf, cg2, cb2, bufB);

    // 9) FC1 + gelu -> hid (bufC)
    gemm_bt<1><<<dim3(HID / 128, T / 128), 256, 0, stream>>>(bufB, wfc1T, cb_fc1, nullptr,
                                                             bufC, T, HID, C);
    // 10) FC2 + residual(y) -> final (bufB)
    gemm_bt<2><<<dim3(C / 128, T / 128), 256, 0, stream>>>(bufC, wfc2T, cb_fc2, ybuf,
                                                           bufB, T, C, HID);
    // 11) final transpose to NCHW (dtype per flag)
    out_transpose<<<dim3(196, 6, 8), 256, 0, stream>>>(bufB, d_out, flag);
}

// Round 4
// 1280.781 us; speedup vs baseline: 1.0446x; 1.0446x over previous
//
#include <hip/hip_runtime.h>
#include <cstdint>
#include <cmath>

using u16 = unsigned short;

typedef __bf16 bf16x8 __attribute__((ext_vector_type(8)));
typedef float  f32x4  __attribute__((ext_vector_type(4)));

__device__ __forceinline__ float b2f(u16 u) {
    return __uint_as_float(((unsigned int)u) << 16);
}
__device__ __forceinline__ u16 f2b(float f) {
    unsigned int x = __float_as_uint(f);
    unsigned int r = (x + 0x7fffu + ((x >> 16) & 1u)) >> 16;
    return (u16)r;
}

// async global->LDS, 16B per lane; LDS dest is wave-uniform base + lane*16.
__device__ __forceinline__ void gload16(const u16* g, u16* l) {
    __builtin_amdgcn_global_load_lds((__attribute__((address_space(1))) void*)g,
                                     (__attribute__((address_space(3))) void*)l,
                                     16, 0, 0);
}

// wave-local LDS RAW fence: drain ds ops, pin scheduling (rule #18).
#define LGKM0_FENCE() do { \
    asm volatile("s_waitcnt lgkmcnt(0)" ::: "memory"); \
    __builtin_amdgcn_sched_barrier(0); } while (0)

// exact-enough gelu: erf via Abramowitz-Stegun 7.1.26 (|err| <= 1.5e-7).
__device__ __forceinline__ float gelu_f(float x) {
    float z = fabsf(x) * 0.70710678118f;
    float t = __builtin_amdgcn_rcpf(fmaf(0.3275911f, z, 1.0f));
    float poly = fmaf(fmaf(fmaf(fmaf(1.061405429f, t, -1.453152027f),
                               t, 1.421413741f),
                          t, -0.284496736f),
                     t, 0.254829592f) * t;
    float e = __expf(-z * z);
    float erfv = copysignf(1.0f - poly * e, x);
    return 0.5f * x * (1.0f + erfv);
}

// token permutation: original (b, hw) -> window-gathered index t'
__device__ __forceinline__ int tprime(int b, int hw) {
    int r = hw / 112, c = hw - r * 112;
    int wy = r / 7, iy = r - wy * 7;
    int wx = c / 7, ix = c - wx * 7;
    return (b * 256 + wy * 16 + wx) * 49 + iy * 7 + ix;
}

// ---------------------------------------------------------------------------
// Input dtype detection: f32 N(0,1) data has exponent field in ~[117,130];
// bf16 pairs read as f32 decode to exponents ~250+. Writes 1 if f32.
__global__ void detect_dtype(const unsigned int* __restrict__ x, int* __restrict__ flag) {
    __shared__ int cnt[256];
    int tid = threadIdx.x;
    int c = 0;
#pragma unroll
    for (int i = 0; i < 16; ++i) {
        unsigned int w = x[tid * 16 + i];
        int e = (w >> 23) & 0xFF;
        if (e >= 100 && e <= 150) ++c;
    }
    cnt[tid] = c;
    __syncthreads();
    if (tid == 0) {
        int s = 0;
        for (int i = 0; i < 256; ++i) s += cnt[i];
        flag[0] = (s > 3072) ? 1 : 0;
    }
}

// Convert any input tensor to canonical bf16 (copy if already bf16).
__global__ void convertk(const void* __restrict__ src, u16* __restrict__ dst, int n,
                         const int* __restrict__ flagp) {
    int isf = flagp[0];
    int i = blockIdx.x * 256 + threadIdx.x;
    if (i < n) dst[i] = isf ? f2b(((const float*)src)[i]) : ((const u16*)src)[i];
}

// ---------------------------------------------------------------------------
// Expanded attention bias: bias_exp[h][row][col] f32 with padding mask baked
// (-1e30 for row>=49 or col>=49). Window-independent -> computed ONCE.
// grid (64,12), block 64: row=blockIdx.x, h=blockIdx.y, col=tid.
__global__ void build_bias(const u16* __restrict__ crpb, float* __restrict__ bias_exp) {
    int row = blockIdx.x, h = blockIdx.y, col = threadIdx.x;
    float v = -1e30f;
    if (row < 49 && col < 49) {
        int ri = row / 7, rj = row - ri * 7;
        int mi = col / 7, mj = col - mi * 7;
        int idx = ((ri - mi + 6) * 13 + (rj - mj + 6)) * 12 + h;
        v = b2f(crpb[idx]);
    }
    bias_exp[(h * 64 + row) * 64 + col] = v;
}

// ---------------------------------------------------------------------------
// Weight transpose: in (K,N) bf16 -> out (N,K).  grid (N/32, K/32), block 256.
__global__ void wtrans(const u16* __restrict__ in, u16* __restrict__ out, int K, int N) {
    __shared__ u16 tile[32][33];
    int n0 = blockIdx.x * 32, k0 = blockIdx.y * 32;
    int tx = threadIdx.x & 31, ty = threadIdx.x >> 5;  // 32 x 8
#pragma unroll
    for (int i = 0; i < 4; ++i)
        tile[ty + i * 8][tx] = in[(size_t)(k0 + ty + i * 8) * N + n0 + tx];
    __syncthreads();
#pragma unroll
    for (int i = 0; i < 4; ++i)
        out[(size_t)(n0 + ty + i * 8) * K + k0 + tx] = tile[tx][ty + i * 8];
}

// ---------------------------------------------------------------------------
// LN1 stats over C for x in (B,C,HW), dtype per flag. One thread per token.
__global__ void ln1_stats(const void* __restrict__ x, float* __restrict__ mean,
                          float* __restrict__ rstd, const int* __restrict__ flagp) {
    int isf = flagp[0];
    int t = blockIdx.x * 256 + threadIdx.x;      // < 100352
    int b = t / 12544, hw = t - b * 12544;
    size_t base = (size_t)b * 384 * 12544 + hw;
    float s = 0.f, sq = 0.f;
    if (isf) {
        const float* p = (const float*)x + base;
        for (int c = 0; c < 384; ++c) {
            float v = p[(size_t)c * 12544];
            s += v; sq += v * v;
        }
    } else {
        const u16* p = (const u16*)x + base;
        for (int c = 0; c < 384; ++c) {
            float v = b2f(p[(size_t)c * 12544]);
            s += v; sq += v * v;
        }
    }
    float m = s * (1.0f / 384.0f);
    float var = sq * (1.0f / 384.0f) - m * m;
    mean[t] = m;
    rstd[t] = rsqrtf(var + 1e-5f);
}

// Transpose + normalize: x(B,C,HW) -> xt(T',C) raw bf16, xn(T',C) normalized
// bf16 — rows written in window-gathered t' order.
// grid (HW/64=196, C/64=6, B=8), block 256.
__global__ void ln1_apply(const void* __restrict__ x, const float* __restrict__ mean,
                          const float* __restrict__ rstd, const u16* __restrict__ g1,
                          const u16* __restrict__ b1, u16* __restrict__ xt,
                          u16* __restrict__ xn, const int* __restrict__ flagp) {
    __shared__ float tile[64][65];
    int isf = flagp[0];
    int hw0 = blockIdx.x * 64, c0 = blockIdx.y * 64, b = blockIdx.z;
    int tid = threadIdx.x;
    {
        int hl = tid & 63, cq = tid >> 6;
        size_t base = ((size_t)b * 384 + c0) * 12544 + hw0;
#pragma unroll
        for (int it = 0; it < 16; ++it) {
            int cl = cq * 16 + it;
            size_t idx = base + (size_t)cl * 12544 + hl;
            tile[cl][hl] = isf ? ((const float*)x)[idx] : b2f(((const u16*)x)[idx]);
        }
    }
    __syncthreads();
    {
        int cl = tid & 63, hq = tid >> 6;
        float g = b2f(g1[c0 + cl]), bb = b2f(b1[c0 + cl]);
#pragma unroll
        for (int it = 0; it < 16; ++it) {
            int hl = hq * 16 + it;
            int hw = hw0 + hl;
            int t = b * 12544 + hw;                 // original order (stats)
            int tp = tprime(b, hw);                 // window-gathered order
            float v = tile[cl][hl];
            size_t o = (size_t)tp * 384 + c0 + cl;
            xt[o] = f2b(v);
            xn[o] = f2b((v - mean[t]) * rstd[t] * g + bb);
        }
    }
}

// ---------------------------------------------------------------------------
// bf16 GEMM: C = A(MxK) * Bt(NxK)^T + bias.
// Double-buffered global_load_lds staging, ONE barrier per K-step (loads for
// step t+1 overlap MFMA of step t). 128x128 tile, BK=32. XCD-aware bijective
// block swizzle. Conflict-free LDS-staged f32 epilogue (stride 132) with
// coalesced 16B stores. EPI 0: bias. 1: bias+gelu. 2: bias+res add.
template <int EPI>
__global__ void gemm_bt(const u16* __restrict__ A, const u16* __restrict__ Bt,
                        const u16* __restrict__ bias, const u16* __restrict__ res,
                        u16* __restrict__ Cout, int M, int N, int K) {
    __shared__ __align__(16) u16 S[2][2][128 * 32];   // [buf][A/B], 32 KB total
    const int tid = threadIdx.x;
    const int wave = tid >> 6, lane = tid & 63;

    // XCD-aware bijective swizzle of flattened block id (8 XCDs)
    const int nbx = gridDim.x;
    const int nwg = nbx * gridDim.y;
    int flat = blockIdx.y * nbx + blockIdx.x;
    {
        int q = nwg >> 3, r = nwg & 7;
        int xcd = flat & 7, loc = flat >> 3;
        flat = (xcd < r ? xcd * (q + 1) : r * (q + 1) + (xcd - r) * q) + loc;
    }
    const int m0 = (flat / nbx) * 128, n0 = (flat % nbx) * 128;

    const int wm = wave & 1, wn = wave >> 1;
    const int m15 = lane & 15, q4 = lane >> 4;

    // staging: lane i -> row (i>>2), col (i&3)*8 — linear base+lane*16B in LDS.
    const u16* gA = A + (size_t)(m0 + wave * 32 + (lane >> 2)) * K + (lane & 3) * 8;
    const u16* gB = Bt + (size_t)(n0 + wave * 32 + (lane >> 2)) * K + (lane & 3) * 8;

    f32x4 acc[4][4];
#pragma unroll
    for (int i = 0; i < 4; ++i)
#pragma unroll
        for (int j = 0; j < 4; ++j) acc[i][j] = {0.f, 0.f, 0.f, 0.f};

    const int nt = K >> 5;
    // prologue: stage tile 0 into buffer 0
    {
        u16* lA = &S[0][0][(wave * 32) * 32];
        u16* lB = &S[0][1][(wave * 32) * 32];
        gload16(gA, lA);
        gload16(gA + 16 * (size_t)K, lA + 16 * 32);
        gload16(gB, lB);
        gload16(gB + 16 * (size_t)K, lB + 16 * 32);
    }
    __syncthreads();   // drains vmcnt(0): tile 0 visible

    for (int t = 0; t < nt; ++t) {
        const int cur = t & 1;
        if (t + 1 < nt) {   // stage next tile into other buffer (overlaps MFMA)
            const int k0 = (t + 1) << 5;
            u16* lA = &S[cur ^ 1][0][(wave * 32) * 32];
            u16* lB = &S[cur ^ 1][1][(wave * 32) * 32];
            gload16(gA + k0, lA);
            gload16(gA + k0 + 16 * (size_t)K, lA + 16 * 32);
            gload16(gB + k0, lB);
            gload16(gB + k0 + 16 * (size_t)K, lB + 16 * 32);
        }
        bf16x8 af[4], bfr[4];
#pragma unroll
        for (int i = 0; i < 4; ++i)
            af[i] = *(const bf16x8*)&S[cur][0][(wm * 64 + i * 16 + m15) * 32 + q4 * 8];
#pragma unroll
        for (int j = 0; j < 4; ++j)
            bfr[j] = *(const bf16x8*)&S[cur][1][(wn * 64 + j * 16 + m15) * 32 + q4 * 8];
#pragma unroll
        for (int i = 0; i < 4; ++i)
#pragma unroll
            for (int j = 0; j < 4; ++j)
                acc[i][j] = __builtin_amdgcn_mfma_f32_16x16x32_bf16(af[i], bfr[j],
                                                                    acc[i][j], 0, 0, 0);
        __syncthreads();  // drains next-tile loads; guards WAR for buffer reuse
    }

    // Epilogue: 4 passes of 32 rows through a 32x132-stride f32 LDS tile.
    constexpr int CSTR = 132;   // +4 pad: bank shift 4/row -> conflict-free
    float* Cs = (float*)&S[0][0][0];   // 32*132*4 = 16.9 KB (fits in 32 KB)
#pragma unroll
    for (int p = 0; p < 4; ++p) {
        __syncthreads();  // Cs free (main-loop reads / prev pass reads done)
        if (wm == (p >> 1)) {
            const int ibase = (p & 1) * 2;
#pragma unroll
            for (int jj = 0; jj < 4; ++jj) {
                int n = n0 + wn * 64 + jj * 16 + m15;
                float bv = b2f(bias[n]);
#pragma unroll
                for (int ii = 0; ii < 2; ++ii) {
                    int i = ibase + ii;
#pragma unroll
                    for (int r = 0; r < 4; ++r) {
                        float v = acc[i][jj][r] + bv;
                        if (EPI == 1) v = gelu_f(v);
                        Cs[(ii * 16 + q4 * 4 + r) * CSTR + wn * 64 + jj * 16 + m15] = v;
                    }
                }
            }
        }
        __syncthreads();  // staged values visible
#pragma unroll
        for (int it = 0; it < 2; ++it) {
            int r2 = it * 16 + (tid >> 4);
            int c8 = (tid & 15) * 8;
            size_t goff = (size_t)(m0 + p * 32 + r2) * N + n0 + c8;
            f32x4 v0 = *(const f32x4*)&Cs[r2 * CSTR + c8];
            f32x4 v1 = *(const f32x4*)&Cs[r2 * CSTR + c8 + 4];
            uint4 rv = {0u, 0u, 0u, 0u};
            const u16* rp = (const u16*)&rv;
            if (EPI == 2) rv = *(const uint4*)&res[goff];
            u16 outv[8];
#pragma unroll
            for (int e = 0; e < 4; ++e) {
                float a = v0[e];
                if (EPI == 2) a += b2f(rp[e]);
                outv[e] = f2b(a);
                float bq = v1[e];
                if (EPI == 2) bq += b2f(rp[4 + e]);
                outv[4 + e] = f2b(bq);
            }
            *(uint4*)&Cout[goff] = *(const uint4*)outv;
        }
    }
}

// ---------------------------------------------------------------------------
// Window attention, window-gathered token order, barrier-free waves.
// New this round: (1) bias via precomputed bias_exp[12][64][64] f32 with
// coalesced lane pattern (replaces fully-divergent rpb gather + ~900 VALU
// index ops per head-iter); (2) next-head Q/K/V global prefetch issued before
// the lgkm fences (vmcnt traffic hides under softmax/PV of current head).
__global__ __launch_bounds__(256, 3)
void attn_win(const u16* __restrict__ qkv, const float* __restrict__ bias_exp,
              u16* __restrict__ outp) {
    __shared__ __align__(16) u16 lds[4][4096];   // 8 KB per wave
    const int tid = threadIdx.x;
    const int wave = tid >> 6, lane = tid & 63;
    const int t0p = blockIdx.x * 49;
    u16* Vt = &lds[wave][0];   // region reuse: in-order per-wave DS + fences
    u16* Ps = &lds[wave][0];
    u16* Po = &lds[wave][0];
    const int m15 = lane & 15, q4 = lane >> 4;
    const int rr = lane >> 2, dq = lane & 3;
    const float scale = 0.17677669529663687f;  // 1/sqrt(32)
    const u16* wbase = qkv + (size_t)t0p * 1152;

    auto loadQK = [&](int h, bf16x8* qf, bf16x8* kf) {
#pragma unroll
        for (int i = 0; i < 4; ++i) {
            int row = i * 16 + m15;
            int rc = row < 49 ? row : 48;     // clamp: avoids OOB, rows masked
            const u16* g = wbase + (size_t)rc * 1152 + h * 32 + q4 * 8;
            qf[i] = *(const bf16x8*)g;
            kf[i] = *(const bf16x8*)(g + 384);
        }
    };
    auto loadV = [&](int h, uint4* vv) {
#pragma unroll
        for (int p = 0; p < 4; ++p) {
            int n = p * 16 + rr;
            vv[p] = {0u, 0u, 0u, 0u};
            if (n < 49)
                vv[p] = *(const uint4*)(wbase + (size_t)n * 1152 + 768 + h * 32 + dq * 8);
        }
    };

    bf16x8 qfA[4], kfA[4];
    uint4 vvA[4];
    loadQK(wave, qfA, kfA);
    loadV(wave, vvA);

#pragma unroll
    for (int hl = 0; hl < 3; ++hl) {
        const int h = hl * 4 + wave;
        // --- V rows (regs) -> LDS transpose ---
#pragma unroll
        for (int p = 0; p < 4; ++p) {
            int n = p * 16 + rr;
            const u16* pv = (const u16*)&vvA[p];
#pragma unroll
            for (int ii = 0; ii < 8; ++ii) Vt[(dq * 8 + ii) * 64 + n] = pv[ii];
        }
        // --- prefetch next head (vmem; flies across lgkm fences) ---
        bf16x8 qfB[4], kfB[4];
        uint4 vvB[4];
        if (hl < 2) {
            loadQK(h + 4, qfB, kfB);
            loadV(h + 4, vvB);
        }
        LGKM0_FENCE();   // Vt writes drained before vf reads
        bf16x8 vf[2][2];
#pragma unroll
        for (int j = 0; j < 2; ++j)
#pragma unroll
            for (int kk = 0; kk < 2; ++kk)
                vf[j][kk] = *(const bf16x8*)&Vt[(j * 16 + m15) * 64 + kk * 32 + q4 * 8];
        // --- QK^T ---
        f32x4 sc[4][4];
#pragma unroll
        for (int i = 0; i < 4; ++i)
#pragma unroll
            for (int j = 0; j < 4; ++j) {
                sc[i][j] = {0.f, 0.f, 0.f, 0.f};
                sc[i][j] = __builtin_amdgcn_mfma_f32_16x16x32_bf16(qfA[i], kfA[j],
                                                                   sc[i][j], 0, 0, 0);
            }
        // --- scale + bias (coalesced L2 loads; mask baked into table) ---
        const float* bx = bias_exp + h * 4096;
#pragma unroll
        for (int i = 0; i < 4; ++i)
#pragma unroll
            for (int r = 0; r < 4; ++r) {
                int row = i * 16 + q4 * 4 + r;
#pragma unroll
                for (int j = 0; j < 4; ++j)
                    sc[i][j][r] = fmaf(sc[i][j][r], scale, bx[row * 64 + j * 16 + m15]);
            }
        // --- softmax over 64 cols (4 regs x 16 lanes) ---
#pragma unroll
        for (int i = 0; i < 4; ++i) {
#pragma unroll
            for (int r = 0; r < 4; ++r) {
                float mx = fmaxf(fmaxf(sc[i][0][r], sc[i][1][r]),
                                 fmaxf(sc[i][2][r], sc[i][3][r]));
                mx = fmaxf(mx, __shfl_xor(mx, 1));
                mx = fmaxf(mx, __shfl_xor(mx, 2));
                mx = fmaxf(mx, __shfl_xor(mx, 4));
                mx = fmaxf(mx, __shfl_xor(mx, 8));
                float e0 = __expf(sc[i][0][r] - mx);
                float e1 = __expf(sc[i][1][r] - mx);
                float e2 = __expf(sc[i][2][r] - mx);
                float e3 = __expf(sc[i][3][r] - mx);
                float sum = e0 + e1 + e2 + e3;
                sum += __shfl_xor(sum, 1);
                sum += __shfl_xor(sum, 2);
                sum += __shfl_xor(sum, 4);
                sum += __shfl_xor(sum, 8);
                float inv = 1.0f / sum;
                sc[i][0][r] = e0 * inv;
                sc[i][1][r] = e1 * inv;
                sc[i][2][r] = e2 * inv;
                sc[i][3][r] = e3 * inv;
            }
        }
        // --- P -> LDS (layout change); vf already in registers ---
#pragma unroll
        for (int i = 0; i < 4; ++i)
#pragma unroll
            for (int r = 0; r < 4; ++r)
#pragma unroll
                for (int j = 0; j < 4; ++j)
                    Ps[(i * 16 + q4 * 4 + r) * 64 + j * 16 + m15] = f2b(sc[i][j][r]);
        LGKM0_FENCE();   // P writes drained before pf reads
        // --- PV ---
        f32x4 oacc[4][2];
#pragma unroll
        for (int i = 0; i < 4; ++i)
#pragma unroll
            for (int j = 0; j < 2; ++j) oacc[i][j] = {0.f, 0.f, 0.f, 0.f};
#pragma unroll
        for (int i = 0; i < 4; ++i) {
#pragma unroll
            for (int kk = 0; kk < 2; ++kk) {
                bf16x8 pf = *(const bf16x8*)&Ps[(i * 16 + m15) * 64 + kk * 32 + q4 * 8];
#pragma unroll
                for (int j = 0; j < 2; ++j)
                    oacc[i][j] = __builtin_amdgcn_mfma_f32_16x16x32_bf16(pf, vf[j][kk],
                                                                         oacc[i][j], 0, 0, 0);
            }
        }
        // --- stage output tile (49x32) in LDS, stride 40 u16 (80B, 16-align) ---
#pragma unroll
        for (int i = 0; i < 4; ++i)
#pragma unroll
            for (int r = 0; r < 4; ++r) {
                int row = i * 16 + q4 * 4 + r;
#pragma unroll
                for (int j = 0; j < 2; ++j)
                    Po[row * 40 + j * 16 + m15] = f2b(oacc[i][j][r]);
            }
        LGKM0_FENCE();   // Po writes drained before coalesced read-out
        // --- full-line coalesced store: 4 lanes x 16B = 64B per row ---
#pragma unroll
        for (int w2 = 0; w2 < 4; ++w2) {
            int row = w2 * 16 + rr;
            if (row < 49) {
                uint4 ov = *(const uint4*)&Po[row * 40 + dq * 8];
                *(uint4*)&outp[(size_t)(t0p + row) * 384 + h * 32 + dq * 8] = ov;
            }
        }
        // --- rotate prefetched registers ---
        if (hl < 2) {
#pragma unroll
            for (int i = 0; i < 4; ++i) {
                qfA[i] = qfB[i];
                kfA[i] = kfB[i];
                vvA[i] = vvB[i];
            }
        }
    }
}

// ---------------------------------------------------------------------------
// LN2: y(T,384) bf16 -> out(T,384) bf16. One wave per token.
__global__ void ln2_kernel(const u16* __restrict__ y, const u16* __restrict__ g2,
                           const u16* __restrict__ b2, u16* __restrict__ out) {
    int wave = threadIdx.x >> 6, lane = threadIdx.x & 63;
    size_t t = (size_t)blockIdx.x * 4 + wave;
    const u16* row = y + t * 384;
    float v[6];
    float s = 0.f, sq = 0.f;
#pragma unroll
    for (int i = 0; i < 6; ++i) {
        v[i] = b2f(row[lane + i * 64]);
        s += v[i]; sq += v[i] * v[i];
    }
#pragma unroll
    for (int m = 1; m < 64; m <<= 1) {
        s += __shfl_xor(s, m);
        sq += __shfl_xor(sq, m);
    }
    float mean = s * (1.0f / 384.0f);
    float var = sq * (1.0f / 384.0f) - mean * mean;
    float rstd = rsqrtf(var + 1e-5f);
#pragma unroll
    for (int i = 0; i < 6; ++i) {
        int c = lane + i * 64;
        out[t * 384 + c] = f2b((v[i] - mean) * rstd * b2f(g2[c]) + b2f(b2[c]));
    }
}

// ---------------------------------------------------------------------------
// final (T',384) bf16 (window-gathered rows) -> out (B,384,112,112).
// grid (196,6,8), block 256.
__global__ void out_transpose(const u16* __restrict__ fin, void* __restrict__ out,
                              const int* __restrict__ flagp) {
    __shared__ float tile[64][65];
    int isf = flagp[0];
    int hw0 = blockIdx.x * 64, c0 = blockIdx.y * 64, b = blockIdx.z;
    int tid = threadIdx.x;
    {
        int cl = tid & 63, hq = tid >> 6;
#pragma unroll
        for (int it = 0; it < 16; ++it) {
            int hl = hq * 16 + it;
            int tp = tprime(b, hw0 + hl);
            tile[hl][cl] = b2f(fin[(size_t)tp * 384 + c0 + cl]);
        }
    }
    __syncthreads();
    {
        int hl = tid & 63, cq = tid >> 6;
#pragma unroll
        for (int it = 0; it < 16; ++it) {
            int cl = cq * 16 + it;
            size_t o = ((size_t)b * 384 + c0 + cl) * 12544 + hw0 + hl;
            float v = tile[hl][cl];
            if (isf) ((float*)out)[o] = v;
            else     ((u16*)out)[o] = f2b(v);
        }
    }
}

// ---------------------------------------------------------------------------
extern "C" void kernel_launch(void* const* d_in, const int* in_sizes, int n_in,
                              void* d_out, int out_size, void* d_ws, size_t ws_size,
                              hipStream_t stream) {
    constexpr int T = 100352, C = 384, HID = 1536, NQ = 1152;
    const void* x      = d_in[0];
    u16* out_any = (u16*)d_out;  // dtype resolved device-side
    (void)out_any;

    char* ws = (char*)d_ws;
    size_t off = 0;
    auto alloc = [&](size_t bytes) { char* p = ws + off; off += (bytes + 255) & ~(size_t)255; return p; };
    int*   flag   = (int*)alloc(4);
    // canonical bf16 copies of all non-x inputs
    u16* cw_qkv  = (u16*)alloc((size_t)C * NQ * 2);
    u16* cb_qkv  = (u16*)alloc((size_t)NQ * 2);
    u16* crpb    = (u16*)alloc((size_t)169 * 12 * 2);
    u16* cw_proj = (u16*)alloc((size_t)C * C * 2);
    u16* cb_proj = (u16*)alloc((size_t)C * 2);
    u16* cg1     = (u16*)alloc((size_t)C * 2);
    u16* cb1     = (u16*)alloc((size_t)C * 2);
    u16* cg2     = (u16*)alloc((size_t)C * 2);
    u16* cb2     = (u16*)alloc((size_t)C * 2);
    u16* cw_fc1  = (u16*)alloc((size_t)C * HID * 2);
    u16* cb_fc1  = (u16*)alloc((size_t)HID * 2);
    u16* cw_fc2  = (u16*)alloc((size_t)HID * C * 2);
    u16* cb_fc2  = (u16*)alloc((size_t)C * 2);
    // transposed weights
    u16* wqkvT  = (u16*)alloc((size_t)C * NQ * 2);
    u16* wprojT = (u16*)alloc((size_t)C * C * 2);
    u16* wfc1T  = (u16*)alloc((size_t)C * HID * 2);
    u16* wfc2T  = (u16*)alloc((size_t)HID * C * 2);
    // expanded bias table
    float* biasx = (float*)alloc((size_t)12 * 64 * 64 * 4);
    // activations (all token-major buffers in window-gathered t' order)
    u16*   xt     = (u16*)alloc((size_t)T * C * 2);
    u16*   bufB   = (u16*)alloc((size_t)T * C * 2);    // xn -> attnout -> h_in -> final
    u16*   bufC   = (u16*)alloc((size_t)T * HID * 2);  // qkv -> hid
    u16*   ybuf   = (u16*)alloc((size_t)T * C * 2);
    float* meanb  = (float*)alloc((size_t)T * 4);
    float* rstdb  = (float*)alloc((size_t)T * 4);

    // 1) detect input dtype from x
    detect_dtype<<<1, 256, 0, stream>>>((const unsigned int*)x, flag);

    // 2) canonicalize all non-x inputs to bf16
    auto conv = [&](const void* src, u16* dst, int n) {
        convertk<<<(n + 255) / 256, 256, 0, stream>>>(src, dst, n, flag);
    };
    conv(d_in[1], cg1, C);
    conv(d_in[2], cb1, C);
    conv(d_in[3], cw_qkv, C * NQ);
    conv(d_in[4], cb_qkv, NQ);
    conv(d_in[5], crpb, 169 * 12);
    conv(d_in[6], cw_proj, C * C);
    conv(d_in[7], cb_proj, C);
    conv(d_in[8], cg2, C);
    conv(d_in[9], cb2, C);
    conv(d_in[10], cw_fc1, C * HID);
    conv(d_in[11], cb_fc1, HID);
    conv(d_in[12], cw_fc2, HID * C);
    conv(d_in[13], cb_fc2, C);

    // 2b) expanded bias table (window-independent, mask baked)
    build_bias<<<dim3(64, 12), 64, 0, stream>>>(crpb, biasx);

    // 3) weight transposes (B^T layout for GEMM)
    wtrans<<<dim3(NQ / 32, C / 32), 256, 0, stream>>>(cw_qkv, wqkvT, C, NQ);
    wtrans<<<dim3(C / 32, C / 32), 256, 0, stream>>>(cw_proj, wprojT, C, C);
    wtrans<<<dim3(HID / 32, C / 32), 256, 0, stream>>>(cw_fc1, wfc1T, C, HID);
    wtrans<<<dim3(C / 32, HID / 32), 256, 0, stream>>>(cw_fc2, wfc2T, HID, C);

    // 4) LN1 + transpose (outputs in window-gathered t' order)
    ln1_stats<<<T / 256, 256, 0, stream>>>(x, meanb, rstdb, flag);
    ln1_apply<<<dim3(196, 6, 8), 256, 0, stream>>>(x, meanb, rstdb, cg1, cb1, xt, bufB, flag);

    // 5) QKV
    gemm_bt<0><<<dim3(NQ / 128, T / 128), 256, 0, stream>>>(bufB, wqkvT, cb_qkv, nullptr,
                                                            bufC, T, NQ, C);
    // 6) attention (qkv in bufC -> attnout in bufB), dense per-window rows
    attn_win<<<2048, 256, 0, stream>>>(bufC, biasx, bufB);

    // 7) proj + residual(xt) -> y
    gemm_bt<2><<<dim3(C / 128, T / 128), 256, 0, stream>>>(bufB, wprojT, cb_proj, xt,
                                                           ybuf, T, C, C);
    // 8) LN2 -> bufB
    ln2_kernel<<<T / 4, 256, 0, stream>>>(ybuf, cg2, cb2, bufB);

    // 9) FC1 + gelu -> hid (bufC)
    gemm_bt<1><<<dim3(HID / 128, T / 128), 256, 0, stream>>>(bufB, wfc1T, cb_fc1, nullptr,
                                                             bufC, T, HID, C);
    // 10) FC2 + residual(y) -> final (bufB)
    gemm_bt<2><<<dim3(C / 128, T / 128), 256, 0, stream>>>(bufC, wfc2T, cb_fc2, ybuf,
                                                           bufB, T, C, HID);
    // 11) final transpose to NCHW (dtype per flag)
    out_transpose<<<dim3(196, 6, 8), 256, 0, stream>>>(bufB, d_out, flag);
}

// Round 6
// 1259.463 us; speedup vs baseline: 1.0623x; 1.0169x over previous
//
#include <hip/hip_runtime.h>
#include <cstdint>
#include <cmath>

using u16 = unsigned short;

typedef __bf16 bf16x8 __attribute__((ext_vector_type(8)));
typedef float  f32x4  __attribute__((ext_vector_type(4)));

__device__ __forceinline__ float b2f(u16 u) {
    return __uint_as_float(((unsigned int)u) << 16);
}
__device__ __forceinline__ u16 f2b(float f) {
    unsigned int x = __float_as_uint(f);
    unsigned int r = (x + 0x7fffu + ((x >> 16) & 1u)) >> 16;
    return (u16)r;
}
// RTNE f32->bf16 via native convert (bit-identical to f2b for non-NaN).
__device__ __forceinline__ u16 f2b_fast(float f) {
    union { __bf16 h; u16 u; } cv;
    cv.h = (__bf16)f;
    return cv.u;
}

// async global->LDS, 16B per lane; LDS dest is wave-uniform base + lane*16.
__device__ __forceinline__ void gload16(const u16* g, u16* l) {
    __builtin_amdgcn_global_load_lds((__attribute__((address_space(1))) void*)g,
                                     (__attribute__((address_space(3))) void*)l,
                                     16, 0, 0);
}

// wave-local LDS RAW fence: drain ds ops, pin scheduling (rule #18).
#define LGKM0_FENCE() do { \
    asm volatile("s_waitcnt lgkmcnt(0)" ::: "memory"); \
    __builtin_amdgcn_sched_barrier(0); } while (0)

// exact-enough gelu: erf via Abramowitz-Stegun 7.1.26 (|err| <= 1.5e-7).
__device__ __forceinline__ float gelu_f(float x) {
    float z = fabsf(x) * 0.70710678118f;
    float t = __builtin_amdgcn_rcpf(fmaf(0.3275911f, z, 1.0f));
    float poly = fmaf(fmaf(fmaf(fmaf(1.061405429f, t, -1.453152027f),
                               t, 1.421413741f),
                          t, -0.284496736f),
                     t, 0.254829592f) * t;
    float e = __expf(-z * z);
    float erfv = copysignf(1.0f - poly * e, x);
    return 0.5f * x * (1.0f + erfv);
}

// token permutation: original (b, hw) -> window-gathered index t'
__device__ __forceinline__ int tprime(int b, int hw) {
    int r = hw / 112, c = hw - r * 112;
    int wy = r / 7, iy = r - wy * 7;
    int wx = c / 7, ix = c - wx * 7;
    return (b * 256 + wy * 16 + wx) * 49 + iy * 7 + ix;
}

// ---------------------------------------------------------------------------
// Input dtype detection: f32 N(0,1) data has exponent field in ~[117,130];
// bf16 pairs read as f32 decode to exponents ~250+. Writes 1 if f32.
__global__ void detect_dtype(const unsigned int* __restrict__ x, int* __restrict__ flag) {
    __shared__ int cnt[256];
    int tid = threadIdx.x;
    int c = 0;
#pragma unroll
    for (int i = 0; i < 16; ++i) {
        unsigned int w = x[tid * 16 + i];
        int e = (w >> 23) & 0xFF;
        if (e >= 100 && e <= 150) ++c;
    }
    cnt[tid] = c;
    __syncthreads();
    if (tid == 0) {
        int s = 0;
        for (int i = 0; i < 256; ++i) s += cnt[i];
        flag[0] = (s > 3072) ? 1 : 0;
    }
}

// ---------------------------------------------------------------------------
// Fused small-tensor prep: convert all 1-D params to bf16 + build the expanded
// attention bias table bias_exp[12][64][64] f32 (mask baked: -1e30 outside
// 49x49) straight from the original-dtype rpb. ONE block, 256 threads.
__global__ void prep_small(const void* g1, const void* b1, const void* bqkv,
                           const void* bproj, const void* g2, const void* b2,
                           const void* bfc1, const void* bfc2, const void* rpb,
                           u16* cg1, u16* cb1, u16* cbqkv, u16* cbproj,
                           u16* cg2, u16* cb2, u16* cbfc1, u16* cbfc2,
                           float* bias_exp, const int* __restrict__ flagp) {
    int isf = flagp[0];
    int tid = threadIdx.x;
    auto cv = [&](const void* s, int i) {
        return isf ? f2b(((const float*)s)[i]) : ((const u16*)s)[i];
    };
    for (int i = tid; i < 384; i += 256) cg1[i] = cv(g1, i);
    for (int i = tid; i < 384; i += 256) cb1[i] = cv(b1, i);
    for (int i = tid; i < 1152; i += 256) cbqkv[i] = cv(bqkv, i);
    for (int i = tid; i < 384; i += 256) cbproj[i] = cv(bproj, i);
    for (int i = tid; i < 384; i += 256) cg2[i] = cv(g2, i);
    for (int i = tid; i < 384; i += 256) cb2[i] = cv(b2, i);
    for (int i = tid; i < 1536; i += 256) cbfc1[i] = cv(bfc1, i);
    for (int i = tid; i < 384; i += 256) cbfc2[i] = cv(bfc2, i);
    for (int i = tid; i < 12 * 64 * 64; i += 256) {
        int h = i >> 12, row = (i >> 6) & 63, col = i & 63;
        float v = -1e30f;
        if (row < 49 && col < 49) {
            int ri = row / 7, rj = row - ri * 7;
            int mi = col / 7, mj = col - mi * 7;
            int idx = ((ri - mi + 6) * 13 + (rj - mj + 6)) * 12 + h;
            v = isf ? ((const float*)rpb)[idx] : b2f(((const u16*)rpb)[idx]);
        }
        bias_exp[i] = v;
    }
}

// ---------------------------------------------------------------------------
// Fused weight transpose: reads ORIGINAL dtype (K,N) -> bf16 (N,K).
// grid (48,48,4): z selects {qkv, proj, fc1, fc2}; out-of-range tiles exit
// (uniform per block -> no partial-barrier hazard).
__global__ void prep_w(const void* w0, const void* w1, const void* w2, const void* w3,
                       u16* o0, u16* o1, u16* o2, u16* o3,
                       const int* __restrict__ flagp) {
    __shared__ u16 tile[32][33];
    int isf = flagp[0];
    const void* src; u16* dst; int K, N;
    switch (blockIdx.z) {
        case 0: src = w0; dst = o0; K = 384;  N = 1152; break;
        case 1: src = w1; dst = o1; K = 384;  N = 384;  break;
        case 2: src = w2; dst = o2; K = 384;  N = 1536; break;
        default: src = w3; dst = o3; K = 1536; N = 384; break;
    }
    if ((int)blockIdx.x >= N / 32 || (int)blockIdx.y >= K / 32) return;
    int n0 = blockIdx.x * 32, k0 = blockIdx.y * 32;
    int tx = threadIdx.x & 31, ty = threadIdx.x >> 5;  // 32 x 8
#pragma unroll
    for (int i = 0; i < 4; ++i) {
        size_t idx = (size_t)(k0 + ty + i * 8) * N + n0 + tx;
        tile[ty + i * 8][tx] = isf ? f2b(((const float*)src)[idx])
                                   : ((const u16*)src)[idx];
    }
    __syncthreads();
#pragma unroll
    for (int i = 0; i < 4; ++i)
        dst[(size_t)(n0 + ty + i * 8) * K + k0 + tx] = tile[tx][ty + i * 8];
}

// ---------------------------------------------------------------------------
// Fused LN1: single pass over x (B,C,HW). Per block: 64 tokens x 384 channels.
// Phase 1: strided stats read (coalesced). Phase 2: 6 chunk passes re-reading
// the (now L2/L1-hot) tile through LDS f32 (exact f32 normalize), writing
// xt (raw bf16) + xn (normalized bf16) in window-gathered t' row order.
// grid (196, 8), block 256.
__global__ void ln1_fused(const void* __restrict__ x, const u16* __restrict__ g1,
                          const u16* __restrict__ b1, u16* __restrict__ xt,
                          u16* __restrict__ xn, const int* __restrict__ flagp) {
    __shared__ float tile[64][66];
    __shared__ float part[4][64];
    __shared__ float part2[4][64];
    __shared__ float stat[2][64];
    int isf = flagp[0];
    int hw0 = blockIdx.x * 64, b = blockIdx.y;
    int tid = threadIdx.x, hl = tid & 63, cq = tid >> 6;
    size_t base = (size_t)b * 384 * 12544 + hw0 + hl;
    float s = 0.f, sq = 0.f;
    for (int ci = 0; ci < 96; ++ci) {
        int c = cq * 96 + ci;
        float v = isf ? ((const float*)x)[base + (size_t)c * 12544]
                      : b2f(((const u16*)x)[base + (size_t)c * 12544]);
        s += v; sq += v * v;
    }
    part[cq][hl] = s;
    part2[cq][hl] = sq;
    __syncthreads();
    if (tid < 64) {
        float S1 = part[0][tid] + part[1][tid] + part[2][tid] + part[3][tid];
        float S2 = part2[0][tid] + part2[1][tid] + part2[2][tid] + part2[3][tid];
        float m = S1 * (1.0f / 384.0f);
        float var = S2 * (1.0f / 384.0f) - m * m;
        stat[0][tid] = m;
        stat[1][tid] = rsqrtf(var + 1e-5f);
    }
    __syncthreads();
    for (int ch = 0; ch < 6; ++ch) {
#pragma unroll
        for (int k = 0; k < 16; ++k) {
            int c = ch * 64 + cq * 16 + k;
            float v = isf ? ((const float*)x)[base + (size_t)c * 12544]
                          : b2f(((const u16*)x)[base + (size_t)c * 12544]);
            tile[cq * 16 + k][hl] = v;
        }
        __syncthreads();
        // write phase: wave cq handles tokens [cq*16, cq*16+16); lane hl = c.
#pragma unroll
        for (int k2 = 0; k2 < 16; ++k2) {
            int tok = cq * 16 + k2;
            int tp = tprime(b, hw0 + tok);
            float m = stat[0][tok], rs = stat[1][tok];
            int c = ch * 64 + hl;
            float v = tile[hl][tok];
            float g = b2f(g1[c]), bb = b2f(b1[c]);
            size_t o = (size_t)tp * 384 + c;
            xt[o] = f2b_fast(v);
            xn[o] = f2b_fast((v - m) * rs * g + bb);
        }
        __syncthreads();
    }
}

// ---------------------------------------------------------------------------
// bf16 GEMM: C = A(MxK) * Bt(NxK)^T + bias. N,K compile-time.
// Double-buffered global_load_lds staging, ONE barrier per K-step. 128x128
// tile, BK=32. XCD-aware bijective block swizzle.
// EPI 0: bias. 1: bias+gelu. 2: bias+res add.
// EPI 0/1 epilogue: wave-private bf16 stage in the 32KB S (stride-64 rows ->
// readback is a contiguous-1KB conflict-free ds_read_b128 pattern), ZERO
// epilogue barriers, full-128B coalesced stores. Single rounding preserved.
// EPI 2 keeps the proven f32 CSTR=132 cross-wave path (residual in f32).
template <int EPI, int N, int K>
__global__ void gemm_bt(const u16* __restrict__ A, const u16* __restrict__ Bt,
                        const u16* __restrict__ bias, const u16* __restrict__ res,
                        u16* __restrict__ Cout, int M) {
    __shared__ __align__(16) u16 S[2][2][128 * 32];   // [buf][A/B], 32 KB total
    const int tid = threadIdx.x;
    const int wave = tid >> 6, lane = tid & 63;

    // XCD-aware bijective swizzle of flattened block id (8 XCDs)
    const int nbx = gridDim.x;
    const int nwg = nbx * gridDim.y;
    int flat = blockIdx.y * nbx + blockIdx.x;
    {
        int q = nwg >> 3, r = nwg & 7;
        int xcd = flat & 7, loc = flat >> 3;
        flat = (xcd < r ? xcd * (q + 1) : r * (q + 1) + (xcd - r) * q) + loc;
    }
    const int m0 = (flat / nbx) * 128, n0 = (flat % nbx) * 128;

    const int wm = wave & 1, wn = wave >> 1;
    const int m15 = lane & 15, q4 = lane >> 4;

    // staging: lane i -> row (i>>2), col (i&3)*8 — linear base+lane*16B in LDS.
    const u16* gA = A + (size_t)(m0 + wave * 32 + (lane >> 2)) * K + (lane & 3) * 8;
    const u16* gB = Bt + (size_t)(n0 + wave * 32 + (lane >> 2)) * K + (lane & 3) * 8;

    f32x4 acc[4][4];
#pragma unroll
    for (int i = 0; i < 4; ++i)
#pragma unroll
        for (int j = 0; j < 4; ++j) acc[i][j] = {0.f, 0.f, 0.f, 0.f};

    constexpr int nt = K >> 5;
    // prologue: stage tile 0 into buffer 0
    {
        u16* lA = &S[0][0][(wave * 32) * 32];
        u16* lB = &S[0][1][(wave * 32) * 32];
        gload16(gA, lA);
        gload16(gA + 16 * (size_t)K, lA + 16 * 32);
        gload16(gB, lB);
        gload16(gB + 16 * (size_t)K, lB + 16 * 32);
    }
    __syncthreads();   // drains vmcnt(0): tile 0 visible

    for (int t = 0; t < nt; ++t) {
        const int cur = t & 1;
        if (t + 1 < nt) {   // stage next tile into other buffer (overlaps MFMA)
            const int k0 = (t + 1) << 5;
            u16* lA = &S[cur ^ 1][0][(wave * 32) * 32];
            u16* lB = &S[cur ^ 1][1][(wave * 32) * 32];
            gload16(gA + k0, lA);
            gload16(gA + k0 + 16 * (size_t)K, lA + 16 * 32);
            gload16(gB + k0, lB);
            gload16(gB + k0 + 16 * (size_t)K, lB + 16 * 32);
        }
        bf16x8 af[4], bfr[4];
#pragma unroll
        for (int i = 0; i < 4; ++i)
            af[i] = *(const bf16x8*)&S[cur][0][(wm * 64 + i * 16 + m15) * 32 + q4 * 8];
#pragma unroll
        for (int j = 0; j < 4; ++j)
            bfr[j] = *(const bf16x8*)&S[cur][1][(wn * 64 + j * 16 + m15) * 32 + q4 * 8];
#pragma unroll
        for (int i = 0; i < 4; ++i)
#pragma unroll
            for (int j = 0; j < 4; ++j)
                acc[i][j] = __builtin_amdgcn_mfma_f32_16x16x32_bf16(af[i], bfr[j],
                                                                    acc[i][j], 0, 0, 0);
        __syncthreads();  // drains next-tile loads; guards WAR for buffer reuse
    }
    // (final loop barrier above: all waves' LDS reads done -> S reusable)

    if (EPI <= 1) {
        // wave-private bf16 stage: 64x64 u16, row stride 64 (8 KB per wave).
        u16* W = &S[0][0][0] + wave * 4096;
#pragma unroll
        for (int jj = 0; jj < 4; ++jj) {
            int n = n0 + wn * 64 + jj * 16 + m15;
            float bv = b2f(bias[n]);
#pragma unroll
            for (int i = 0; i < 4; ++i)
#pragma unroll
                for (int r = 0; r < 4; ++r) {
                    float v = acc[i][jj][r] + bv;
                    if (EPI == 1) v = gelu_f(v);
                    W[(i * 16 + q4 * 4 + r) * 64 + jj * 16 + m15] = f2b_fast(v);
                }
        }
        // wave-local ds_write->ds_read ordering handled by compiler lgkmcnt.
#pragma unroll
        for (int o = 0; o < 8; ++o) {
            int lrow = o * 8 + (lane >> 3);
            int c8 = (lane & 7) * 8;
            uint4 v = *(const uint4*)&W[lrow * 64 + c8];
            *(uint4*)&Cout[(size_t)(m0 + wm * 64 + lrow) * N + n0 + wn * 64 + c8] = v;
        }
    } else {
        // Epilogue: 4 passes of 32 rows through a 32x132-stride f32 LDS tile.
        constexpr int CSTR = 132;   // +4 pad: conflict-free
        float* Cs = (float*)&S[0][0][0];
#pragma unroll
        for (int p = 0; p < 4; ++p) {
            __syncthreads();  // Cs free
            if (wm == (p >> 1)) {
                const int ibase = (p & 1) * 2;
#pragma unroll
                for (int jj = 0; jj < 4; ++jj) {
                    int n = n0 + wn * 64 + jj * 16 + m15;
                    float bv = b2f(bias[n]);
#pragma unroll
                    for (int ii = 0; ii < 2; ++ii) {
                        int i = ibase + ii;
#pragma unroll
                        for (int r = 0; r < 4; ++r) {
                            float v = acc[i][jj][r] + bv;
                            Cs[(ii * 16 + q4 * 4 + r) * CSTR + wn * 64 + jj * 16 + m15] = v;
                        }
                    }
                }
            }
            __syncthreads();  // staged values visible
#pragma unroll
            for (int it = 0; it < 2; ++it) {
                int r2 = it * 16 + (tid >> 4);
                int c8 = (tid & 15) * 8;
                size_t goff = (size_t)(m0 + p * 32 + r2) * N + n0 + c8;
                f32x4 v0 = *(const f32x4*)&Cs[r2 * CSTR + c8];
                f32x4 v1 = *(const f32x4*)&Cs[r2 * CSTR + c8 + 4];
                uint4 rv = *(const uint4*)&res[goff];
                const u16* rp = (const u16*)&rv;
                u16 outv[8];
#pragma unroll
                for (int e = 0; e < 4; ++e) {
                    outv[e] = f2b_fast(v0[e] + b2f(rp[e]));
                    outv[4 + e] = f2b_fast(v1[e] + b2f(rp[4 + e]));
                }
                *(uint4*)&Cout[goff] = *(const uint4*)outv;
            }
        }
    }
}

// ---------------------------------------------------------------------------
// Window attention, window-gathered token order, barrier-free waves.
// Bias via precomputed bias_exp[12][64][64] f32 (coalesced, mask baked);
// next-head Q/K/V global prefetch hides HBM latency under softmax/PV.
__global__ __launch_bounds__(256, 3)
void attn_win(const u16* __restrict__ qkv, const float* __restrict__ bias_exp,
              u16* __restrict__ outp) {
    __shared__ __align__(16) u16 lds[4][4096];   // 8 KB per wave
    const int tid = threadIdx.x;
    const int wave = tid >> 6, lane = tid & 63;
    const int t0p = blockIdx.x * 49;
    u16* Vt = &lds[wave][0];   // region reuse: in-order per-wave DS + fences
    u16* Ps = &lds[wave][0];
    u16* Po = &lds[wave][0];
    const int m15 = lane & 15, q4 = lane >> 4;
    const int rr = lane >> 2, dq = lane & 3;
    const float scale = 0.17677669529663687f;  // 1/sqrt(32)
    const u16* wbase = qkv + (size_t)t0p * 1152;

    auto loadQK = [&](int h, bf16x8* qf, bf16x8* kf) {
#pragma unroll
        for (int i = 0; i < 4; ++i) {
            int row = i * 16 + m15;
            int rc = row < 49 ? row : 48;     // clamp: avoids OOB, rows masked
            const u16* g = wbase + (size_t)rc * 1152 + h * 32 + q4 * 8;
            qf[i] = *(const bf16x8*)g;
            kf[i] = *(const bf16x8*)(g + 384);
        }
    };
    auto loadV = [&](int h, uint4* vv) {
#pragma unroll
        for (int p = 0; p < 4; ++p) {
            int n = p * 16 + rr;
            vv[p] = {0u, 0u, 0u, 0u};
            if (n < 49)
                vv[p] = *(const uint4*)(wbase + (size_t)n * 1152 + 768 + h * 32 + dq * 8);
        }
    };

    bf16x8 qfA[4], kfA[4];
    uint4 vvA[4];
    loadQK(wave, qfA, kfA);
    loadV(wave, vvA);

#pragma unroll
    for (int hl = 0; hl < 3; ++hl) {
        const int h = hl * 4 + wave;
        // --- V rows (regs) -> LDS transpose ---
#pragma unroll
        for (int p = 0; p < 4; ++p) {
            int n = p * 16 + rr;
            const u16* pv = (const u16*)&vvA[p];
#pragma unroll
            for (int ii = 0; ii < 8; ++ii) Vt[(dq * 8 + ii) * 64 + n] = pv[ii];
        }
        // --- prefetch next head (vmem; flies across lgkm fences) ---
        bf16x8 qfB[4], kfB[4];
        uint4 vvB[4];
        if (hl < 2) {
            loadQK(h + 4, qfB, kfB);
            loadV(h + 4, vvB);
        }
        LGKM0_FENCE();   // Vt writes drained before vf reads
        bf16x8 vf[2][2];
#pragma unroll
        for (int j = 0; j < 2; ++j)
#pragma unroll
            for (int kk = 0; kk < 2; ++kk)
                vf[j][kk] = *(const bf16x8*)&Vt[(j * 16 + m15) * 64 + kk * 32 + q4 * 8];
        // --- QK^T ---
        f32x4 sc[4][4];
#pragma unroll
        for (int i = 0; i < 4; ++i)
#pragma unroll
            for (int j = 0; j < 4; ++j) {
                sc[i][j] = {0.f, 0.f, 0.f, 0.f};
                sc[i][j] = __builtin_amdgcn_mfma_f32_16x16x32_bf16(qfA[i], kfA[j],
                                                                   sc[i][j], 0, 0, 0);
            }
        // --- scale + bias (coalesced L2 loads; mask baked into table) ---
        const float* bx = bias_exp + h * 4096;
#pragma unroll
        for (int i = 0; i < 4; ++i)
#pragma unroll
            for (int r = 0; r < 4; ++r) {
                int row = i * 16 + q4 * 4 + r;
#pragma unroll
                for (int j = 0; j < 4; ++j)
                    sc[i][j][r] = fmaf(sc[i][j][r], scale, bx[row * 64 + j * 16 + m15]);
            }
        // --- softmax over 64 cols (4 regs x 16 lanes) ---
#pragma unroll
        for (int i = 0; i < 4; ++i) {
#pragma unroll
            for (int r = 0; r < 4; ++r) {
                float mx = fmaxf(fmaxf(sc[i][0][r], sc[i][1][r]),
                                 fmaxf(sc[i][2][r], sc[i][3][r]));
                mx = fmaxf(mx, __shfl_xor(mx, 1));
                mx = fmaxf(mx, __shfl_xor(mx, 2));
                mx = fmaxf(mx, __shfl_xor(mx, 4));
                mx = fmaxf(mx, __shfl_xor(mx, 8));
                float e0 = __expf(sc[i][0][r] - mx);
                float e1 = __expf(sc[i][1][r] - mx);
                float e2 = __expf(sc[i][2][r] - mx);
                float e3 = __expf(sc[i][3][r] - mx);
                float sum = e0 + e1 + e2 + e3;
                sum += __shfl_xor(sum, 1);
                sum += __shfl_xor(sum, 2);
                sum += __shfl_xor(sum, 4);
                sum += __shfl_xor(sum, 8);
                float inv = 1.0f / sum;
                sc[i][0][r] = e0 * inv;
                sc[i][1][r] = e1 * inv;
                sc[i][2][r] = e2 * inv;
                sc[i][3][r] = e3 * inv;
            }
        }
        // --- P -> LDS (layout change); vf already in registers ---
#pragma unroll
        for (int i = 0; i < 4; ++i)
#pragma unroll
            for (int r = 0; r < 4; ++r)
#pragma unroll
                for (int j = 0; j < 4; ++j)
                    Ps[(i * 16 + q4 * 4 + r) * 64 + j * 16 + m15] = f2b(sc[i][j][r]);
        LGKM0_FENCE();   // P writes drained before pf reads
        // --- PV ---
        f32x4 oacc[4][2];
#pragma unroll
        for (int i = 0; i < 4; ++i)
#pragma unroll
            for (int j = 0; j < 2; ++j) oacc[i][j] = {0.f, 0.f, 0.f, 0.f};
#pragma unroll
        for (int i = 0; i < 4; ++i) {
#pragma unroll
            for (int kk = 0; kk < 2; ++kk) {
                bf16x8 pf = *(const bf16x8*)&Ps[(i * 16 + m15) * 64 + kk * 32 + q4 * 8];
#pragma unroll
                for (int j = 0; j < 2; ++j)
                    oacc[i][j] = __builtin_amdgcn_mfma_f32_16x16x32_bf16(pf, vf[j][kk],
                                                                         oacc[i][j], 0, 0, 0);
            }
        }
        // --- stage output tile (49x32) in LDS, stride 40 u16 (80B, 16-align) ---
#pragma unroll
        for (int i = 0; i < 4; ++i)
#pragma unroll
            for (int r = 0; r < 4; ++r) {
                int row = i * 16 + q4 * 4 + r;
#pragma unroll
                for (int j = 0; j < 2; ++j)
                    Po[row * 40 + j * 16 + m15] = f2b(oacc[i][j][r]);
            }
        LGKM0_FENCE();   // Po writes drained before coalesced read-out
        // --- full-line coalesced store: 4 lanes x 16B = 64B per row ---
#pragma unroll
        for (int w2 = 0; w2 < 4; ++w2) {
            int row = w2 * 16 + rr;
            if (row < 49) {
                uint4 ov = *(const uint4*)&Po[row * 40 + dq * 8];
                *(uint4*)&outp[(size_t)(t0p + row) * 384 + h * 32 + dq * 8] = ov;
            }
        }
        // --- rotate prefetched registers ---
        if (hl < 2) {
#pragma unroll
            for (int i = 0; i < 4; ++i) {
                qfA[i] = qfB[i];
                kfA[i] = kfB[i];
                vvA[i] = vvB[i];
            }
        }
    }
}

// ---------------------------------------------------------------------------
// LN2: y(T,384) bf16 -> out(T,384) bf16. One wave per token, vectorized
// 12B/lane loads+stores (was scalar 2B).
__global__ void ln2_kernel(const u16* __restrict__ y, const u16* __restrict__ g2,
                           const u16* __restrict__ b2, u16* __restrict__ out) {
    int wave = threadIdx.x >> 6, lane = threadIdx.x & 63;
    size_t t = (size_t)blockIdx.x * 4 + wave;
    uint3 rv = *(const uint3*)(y + t * 384 + lane * 6);
    float v[6];
    v[0] = b2f((u16)(rv.x & 0xffff)); v[1] = b2f((u16)(rv.x >> 16));
    v[2] = b2f((u16)(rv.y & 0xffff)); v[3] = b2f((u16)(rv.y >> 16));
    v[4] = b2f((u16)(rv.z & 0xffff)); v[5] = b2f((u16)(rv.z >> 16));
    float s = 0.f, sq = 0.f;
#pragma unroll
    for (int i = 0; i < 6; ++i) { s += v[i]; sq += v[i] * v[i]; }
#pragma unroll
    for (int m = 1; m < 64; m <<= 1) {
        s += __shfl_xor(s, m);
        sq += __shfl_xor(sq, m);
    }
    float mean = s * (1.0f / 384.0f);
    float var = sq * (1.0f / 384.0f) - mean * mean;
    float rstd = rsqrtf(var + 1e-5f);
    uint3 gv = *(const uint3*)(g2 + lane * 6);
    uint3 bv = *(const uint3*)(b2 + lane * 6);
    float g[6], bb[6];
    g[0] = b2f((u16)(gv.x & 0xffff)); g[1] = b2f((u16)(gv.x >> 16));
    g[2] = b2f((u16)(gv.y & 0xffff)); g[3] = b2f((u16)(gv.y >> 16));
    g[4] = b2f((u16)(gv.z & 0xffff)); g[5] = b2f((u16)(gv.z >> 16));
    bb[0] = b2f((u16)(bv.x & 0xffff)); bb[1] = b2f((u16)(bv.x >> 16));
    bb[2] = b2f((u16)(bv.y & 0xffff)); bb[3] = b2f((u16)(bv.y >> 16));
    bb[4] = b2f((u16)(bv.z & 0xffff)); bb[5] = b2f((u16)(bv.z >> 16));
    u16 o[6];
#pragma unroll
    for (int i = 0; i < 6; ++i)
        o[i] = f2b_fast((v[i] - mean) * rstd * g[i] + bb[i]);
    uint3 ov;
    ov.x = (unsigned)o[0] | ((unsigned)o[1] << 16);
    ov.y = (unsigned)o[2] | ((unsigned)o[3] << 16);
    ov.z = (unsigned)o[4] | ((unsigned)o[5] << 16);
    *(uint3*)(out + t * 384 + lane * 6) = ov;
}

// ---------------------------------------------------------------------------
// final (T',384) bf16 (window-gathered rows) -> out (B,384,112,112).
// grid (196,6,8), block 256.
__global__ void out_transpose(const u16* __restrict__ fin, void* __restrict__ out,
                              const int* __restrict__ flagp) {
    __shared__ float tile[64][65];
    int isf = flagp[0];
    int hw0 = blockIdx.x * 64, c0 = blockIdx.y * 64, b = blockIdx.z;
    int tid = threadIdx.x;
    {
        int cl = tid & 63, hq = tid >> 6;
#pragma unroll
        for (int it = 0; it < 16; ++it) {
            int hl = hq * 16 + it;
            int tp = tprime(b, hw0 + hl);
            tile[hl][cl] = b2f(fin[(size_t)tp * 384 + c0 + cl]);
        }
    }
    __syncthreads();
    {
        int hl = tid & 63, cq = tid >> 6;
#pragma unroll
        for (int it = 0; it < 16; ++it) {
            int cl = cq * 16 + it;
            size_t o = ((size_t)b * 384 + c0 + cl) * 12544 + hw0 + hl;
            float v = tile[hl][cl];
            if (isf) ((float*)out)[o] = v;
            else     ((u16*)out)[o] = f2b(v);
        }
    }
}

// ---------------------------------------------------------------------------
extern "C" void kernel_launch(void* const* d_in, const int* in_sizes, int n_in,
                              void* d_out, int out_size, void* d_ws, size_t ws_size,
                              hipStream_t stream) {
    constexpr int T = 100352, C = 384, HID = 1536, NQ = 1152;
    const void* x = d_in[0];

    char* ws = (char*)d_ws;
    size_t off = 0;
    auto alloc = [&](size_t bytes) { char* p = ws + off; off += (bytes + 255) & ~(size_t)255; return p; };
    int* flag = (int*)alloc(4);
    // bf16 bias/param vectors
    u16* cb_qkv  = (u16*)alloc((size_t)NQ * 2);
    u16* cb_proj = (u16*)alloc((size_t)C * 2);
    u16* cg1     = (u16*)alloc((size_t)C * 2);
    u16* cb1     = (u16*)alloc((size_t)C * 2);
    u16* cg2     = (u16*)alloc((size_t)C * 2);
    u16* cb2     = (u16*)alloc((size_t)C * 2);
    u16* cb_fc1  = (u16*)alloc((size_t)HID * 2);
    u16* cb_fc2  = (u16*)alloc((size_t)C * 2);
    // transposed bf16 weights (built straight from original dtype)
    u16* wqkvT  = (u16*)alloc((size_t)C * NQ * 2);
    u16* wprojT = (u16*)alloc((size_t)C * C * 2);
    u16* wfc1T  = (u16*)alloc((size_t)C * HID * 2);
    u16* wfc2T  = (u16*)alloc((size_t)HID * C * 2);
    // expanded bias table
    float* biasx = (float*)alloc((size_t)12 * 64 * 64 * 4);
    // activations (token-major, window-gathered t' order)
    u16* xt   = (u16*)alloc((size_t)T * C * 2);
    u16* bufB = (u16*)alloc((size_t)T * C * 2);    // xn -> attnout -> h_in -> final
    u16* bufC = (u16*)alloc((size_t)T * HID * 2);  // qkv -> hid
    u16* ybuf = (u16*)alloc((size_t)T * C * 2);

    // 1) detect input dtype from x
    detect_dtype<<<1, 256, 0, stream>>>((const unsigned int*)x, flag);

    // 2) fused prep: small tensors + bias table; weight transposes
    prep_small<<<1, 256, 0, stream>>>(d_in[1], d_in[2], d_in[4], d_in[7], d_in[8],
                                      d_in[9], d_in[11], d_in[13], d_in[5],
                                      cg1, cb1, cb_qkv, cb_proj, cg2, cb2,
                                      cb_fc1, cb_fc2, biasx, flag);
    prep_w<<<dim3(48, 48, 4), 256, 0, stream>>>(d_in[3], d_in[6], d_in[10], d_in[12],
                                                wqkvT, wprojT, wfc1T, wfc2T, flag);

    // 3) fused LN1 (stats + normalize + transpose, single x pass)
    ln1_fused<<<dim3(196, 8), 256, 0, stream>>>(x, cg1, cb1, xt, bufB, flag);

    // 4) QKV
    gemm_bt<0, NQ, C><<<dim3(NQ / 128, T / 128), 256, 0, stream>>>(
        bufB, wqkvT, cb_qkv, nullptr, bufC, T);
    // 5) attention (qkv in bufC -> attnout in bufB), dense per-window rows
    attn_win<<<2048, 256, 0, stream>>>(bufC, biasx, bufB);

    // 6) proj + residual(xt) -> y
    gemm_bt<2, C, C><<<dim3(C / 128, T / 128), 256, 0, stream>>>(
        bufB, wprojT, cb_proj, xt, ybuf, T);
    // 7) LN2 -> bufB
    ln2_kernel<<<T / 4, 256, 0, stream>>>(ybuf, cg2, cb2, bufB);

    // 8) FC1 + gelu -> hid (bufC)
    gemm_bt<1, HID, C><<<dim3(HID / 128, T / 128), 256, 0, stream>>>(
        bufB, wfc1T, cb_fc1, nullptr, bufC, T);
    // 9) FC2 + residual(y) -> final (bufB)
    gemm_bt<2, C, HID><<<dim3(C / 128, T / 128), 256, 0, stream>>>(
        bufC, wfc2T, cb_fc2, ybuf, bufB, T);
    // 10) final transpose to NCHW (dtype per flag)
    out_transpose<<<dim3(196, 6, 8), 256, 0, stream>>>(bufB, d_out, flag);
}

// Round 7
// 1134.932 us; speedup vs baseline: 1.1789x; 1.1097x over previous
//
#include <hip/hip_runtime.h>
#include <cstdint>
#include <cmath>

using u16 = unsigned short;

typedef __bf16 bf16x8 __attribute__((ext_vector_type(8)));
typedef float  f32x4  __attribute__((ext_vector_type(4)));

__device__ __forceinline__ float b2f(u16 u) {
    return __uint_as_float(((unsigned int)u) << 16);
}
__device__ __forceinline__ u16 f2b(float f) {
    unsigned int x = __float_as_uint(f);
    unsigned int r = (x + 0x7fffu + ((x >> 16) & 1u)) >> 16;
    return (u16)r;
}
// RTNE f32->bf16 via native convert (bit-identical to f2b for non-NaN).
__device__ __forceinline__ u16 f2b_fast(float f) {
    union { __bf16 h; u16 u; } cv;
    cv.h = (__bf16)f;
    return cv.u;
}

// async global->LDS, 16B per lane; LDS dest is wave-uniform base + lane*16.
__device__ __forceinline__ void gload16(const u16* g, u16* l) {
    __builtin_amdgcn_global_load_lds((__attribute__((address_space(1))) void*)g,
                                     (__attribute__((address_space(3))) void*)l,
                                     16, 0, 0);
}

// wave-local LDS RAW fence: drain ds ops, pin scheduling (rule #18).
#define LGKM0_FENCE() do { \
    asm volatile("s_waitcnt lgkmcnt(0)" ::: "memory"); \
    __builtin_amdgcn_sched_barrier(0); } while (0)

// exact-enough gelu: erf via Abramowitz-Stegun 7.1.26 (|err| <= 1.5e-7).
__device__ __forceinline__ float gelu_f(float x) {
    float z = fabsf(x) * 0.70710678118f;
    float t = __builtin_amdgcn_rcpf(fmaf(0.3275911f, z, 1.0f));
    float poly = fmaf(fmaf(fmaf(fmaf(1.061405429f, t, -1.453152027f),
                               t, 1.421413741f),
                          t, -0.284496736f),
                     t, 0.254829592f) * t;
    float e = __expf(-z * z);
    float erfv = copysignf(1.0f - poly * e, x);
    return 0.5f * x * (1.0f + erfv);
}

// token permutation: original (b, hw) -> window-gathered index t'
__device__ __forceinline__ int tprime(int b, int hw) {
    int r = hw / 112, c = hw - r * 112;
    int wy = r / 7, iy = r - wy * 7;
    int wx = c / 7, ix = c - wx * 7;
    return (b * 256 + wy * 16 + wx) * 49 + iy * 7 + ix;
}

// ---------------------------------------------------------------------------
// Input dtype detection: f32 N(0,1) data has exponent field in ~[117,130];
// bf16 pairs read as f32 decode to exponents ~250+. Writes 1 if f32.
__global__ void detect_dtype(const unsigned int* __restrict__ x, int* __restrict__ flag) {
    __shared__ int cnt[256];
    int tid = threadIdx.x;
    int c = 0;
#pragma unroll
    for (int i = 0; i < 16; ++i) {
        unsigned int w = x[tid * 16 + i];
        int e = (w >> 23) & 0xFF;
        if (e >= 100 && e <= 150) ++c;
    }
    cnt[tid] = c;
    __syncthreads();
    if (tid == 0) {
        int s = 0;
        for (int i = 0; i < 256; ++i) s += cnt[i];
        flag[0] = (s > 3072) ? 1 : 0;
    }
}

// ---------------------------------------------------------------------------
// Fused small-tensor prep: convert all 1-D params to bf16 + build the expanded
// attention bias table bias_exp[12][64][64] f32 (mask baked: -1e30 outside
// 49x49) straight from the original-dtype rpb. ONE block, 256 threads.
__global__ void prep_small(const void* g1, const void* b1, const void* bqkv,
                           const void* bproj, const void* g2, const void* b2,
                           const void* bfc1, const void* bfc2, const void* rpb,
                           u16* cg1, u16* cb1, u16* cbqkv, u16* cbproj,
                           u16* cg2, u16* cb2, u16* cbfc1, u16* cbfc2,
                           float* bias_exp, const int* __restrict__ flagp) {
    int isf = flagp[0];
    int tid = threadIdx.x;
    auto cv = [&](const void* s, int i) {
        return isf ? f2b(((const float*)s)[i]) : ((const u16*)s)[i];
    };
    for (int i = tid; i < 384; i += 256) cg1[i] = cv(g1, i);
    for (int i = tid; i < 384; i += 256) cb1[i] = cv(b1, i);
    for (int i = tid; i < 1152; i += 256) cbqkv[i] = cv(bqkv, i);
    for (int i = tid; i < 384; i += 256) cbproj[i] = cv(bproj, i);
    for (int i = tid; i < 384; i += 256) cg2[i] = cv(g2, i);
    for (int i = tid; i < 384; i += 256) cb2[i] = cv(b2, i);
    for (int i = tid; i < 1536; i += 256) cbfc1[i] = cv(bfc1, i);
    for (int i = tid; i < 384; i += 256) cbfc2[i] = cv(bfc2, i);
    for (int i = tid; i < 12 * 64 * 64; i += 256) {
        int h = i >> 12, row = (i >> 6) & 63, col = i & 63;
        float v = -1e30f;
        if (row < 49 && col < 49) {
            int ri = row / 7, rj = row - ri * 7;
            int mi = col / 7, mj = col - mi * 7;
            int idx = ((ri - mi + 6) * 13 + (rj - mj + 6)) * 12 + h;
            v = isf ? ((const float*)rpb)[idx] : b2f(((const u16*)rpb)[idx]);
        }
        bias_exp[i] = v;
    }
}

// ---------------------------------------------------------------------------
// Fused weight transpose: reads ORIGINAL dtype (K,N) -> bf16 (N,K).
// grid (48,48,4): z selects {qkv, proj, fc1, fc2}; out-of-range tiles exit
// (uniform per block -> no partial-barrier hazard).
__global__ void prep_w(const void* w0, const void* w1, const void* w2, const void* w3,
                       u16* o0, u16* o1, u16* o2, u16* o3,
                       const int* __restrict__ flagp) {
    __shared__ u16 tile[32][33];
    int isf = flagp[0];
    const void* src; u16* dst; int K, N;
    switch (blockIdx.z) {
        case 0: src = w0; dst = o0; K = 384;  N = 1152; break;
        case 1: src = w1; dst = o1; K = 384;  N = 384;  break;
        case 2: src = w2; dst = o2; K = 384;  N = 1536; break;
        default: src = w3; dst = o3; K = 1536; N = 384; break;
    }
    if ((int)blockIdx.x >= N / 32 || (int)blockIdx.y >= K / 32) return;
    int n0 = blockIdx.x * 32, k0 = blockIdx.y * 32;
    int tx = threadIdx.x & 31, ty = threadIdx.x >> 5;  // 32 x 8
#pragma unroll
    for (int i = 0; i < 4; ++i) {
        size_t idx = (size_t)(k0 + ty + i * 8) * N + n0 + tx;
        tile[ty + i * 8][tx] = isf ? f2b(((const float*)src)[idx])
                                   : ((const u16*)src)[idx];
    }
    __syncthreads();
#pragma unroll
    for (int i = 0; i < 4; ++i)
        dst[(size_t)(n0 + ty + i * 8) * K + k0 + tx] = tile[tx][ty + i * 8];
}

// ---------------------------------------------------------------------------
// Fused LN1: single pass over x (B,C,HW). Per block: 64 tokens x 384 channels.
// grid (196, 8), block 256.
__global__ void ln1_fused(const void* __restrict__ x, const u16* __restrict__ g1,
                          const u16* __restrict__ b1, u16* __restrict__ xt,
                          u16* __restrict__ xn, const int* __restrict__ flagp) {
    __shared__ float tile[64][66];
    __shared__ float part[4][64];
    __shared__ float part2[4][64];
    __shared__ float stat[2][64];
    int isf = flagp[0];
    int hw0 = blockIdx.x * 64, b = blockIdx.y;
    int tid = threadIdx.x, hl = tid & 63, cq = tid >> 6;
    size_t base = (size_t)b * 384 * 12544 + hw0 + hl;
    float s = 0.f, sq = 0.f;
    for (int ci = 0; ci < 96; ++ci) {
        int c = cq * 96 + ci;
        float v = isf ? ((const float*)x)[base + (size_t)c * 12544]
                      : b2f(((const u16*)x)[base + (size_t)c * 12544]);
        s += v; sq += v * v;
    }
    part[cq][hl] = s;
    part2[cq][hl] = sq;
    __syncthreads();
    if (tid < 64) {
        float S1 = part[0][tid] + part[1][tid] + part[2][tid] + part[3][tid];
        float S2 = part2[0][tid] + part2[1][tid] + part2[2][tid] + part2[3][tid];
        float m = S1 * (1.0f / 384.0f);
        float var = S2 * (1.0f / 384.0f) - m * m;
        stat[0][tid] = m;
        stat[1][tid] = rsqrtf(var + 1e-5f);
    }
    __syncthreads();
    for (int ch = 0; ch < 6; ++ch) {
#pragma unroll
        for (int k = 0; k < 16; ++k) {
            int c = ch * 64 + cq * 16 + k;
            float v = isf ? ((const float*)x)[base + (size_t)c * 12544]
                          : b2f(((const u16*)x)[base + (size_t)c * 12544]);
            tile[cq * 16 + k][hl] = v;
        }
        __syncthreads();
#pragma unroll
        for (int k2 = 0; k2 < 16; ++k2) {
            int tok = cq * 16 + k2;
            int tp = tprime(b, hw0 + tok);
            float m = stat[0][tok], rs = stat[1][tok];
            int c = ch * 64 + hl;
            float v = tile[hl][tok];
            float g = b2f(g1[c]), bb = b2f(b1[c]);
            size_t o = (size_t)tp * 384 + c;
            xt[o] = f2b_fast(v);
            xn[o] = f2b_fast((v - m) * rs * g + bb);
        }
        __syncthreads();
    }
}

// ---------------------------------------------------------------------------
// bf16 GEMM: C = A(MxK) * Bt(NxK)^T + bias. N,K compile-time. (unchanged R6)
template <int EPI, int N, int K>
__global__ void gemm_bt(const u16* __restrict__ A, const u16* __restrict__ Bt,
                        const u16* __restrict__ bias, const u16* __restrict__ res,
                        u16* __restrict__ Cout, int M) {
    __shared__ __align__(16) u16 S[2][2][128 * 32];   // [buf][A/B], 32 KB total
    const int tid = threadIdx.x;
    const int wave = tid >> 6, lane = tid & 63;

    const int nbx = gridDim.x;
    const int nwg = nbx * gridDim.y;
    int flat = blockIdx.y * nbx + blockIdx.x;
    {
        int q = nwg >> 3, r = nwg & 7;
        int xcd = flat & 7, loc = flat >> 3;
        flat = (xcd < r ? xcd * (q + 1) : r * (q + 1) + (xcd - r) * q) + loc;
    }
    const int m0 = (flat / nbx) * 128, n0 = (flat % nbx) * 128;

    const int wm = wave & 1, wn = wave >> 1;
    const int m15 = lane & 15, q4 = lane >> 4;

    const u16* gA = A + (size_t)(m0 + wave * 32 + (lane >> 2)) * K + (lane & 3) * 8;
    const u16* gB = Bt + (size_t)(n0 + wave * 32 + (lane >> 2)) * K + (lane & 3) * 8;

    f32x4 acc[4][4];
#pragma unroll
    for (int i = 0; i < 4; ++i)
#pragma unroll
        for (int j = 0; j < 4; ++j) acc[i][j] = {0.f, 0.f, 0.f, 0.f};

    constexpr int nt = K >> 5;
    {
        u16* lA = &S[0][0][(wave * 32) * 32];
        u16* lB = &S[0][1][(wave * 32) * 32];
        gload16(gA, lA);
        gload16(gA + 16 * (size_t)K, lA + 16 * 32);
        gload16(gB, lB);
        gload16(gB + 16 * (size_t)K, lB + 16 * 32);
    }
    __syncthreads();

    for (int t = 0; t < nt; ++t) {
        const int cur = t & 1;
        if (t + 1 < nt) {
            const int k0 = (t + 1) << 5;
            u16* lA = &S[cur ^ 1][0][(wave * 32) * 32];
            u16* lB = &S[cur ^ 1][1][(wave * 32) * 32];
            gload16(gA + k0, lA);
            gload16(gA + k0 + 16 * (size_t)K, lA + 16 * 32);
            gload16(gB + k0, lB);
            gload16(gB + k0 + 16 * (size_t)K, lB + 16 * 32);
        }
        bf16x8 af[4], bfr[4];
#pragma unroll
        for (int i = 0; i < 4; ++i)
            af[i] = *(const bf16x8*)&S[cur][0][(wm * 64 + i * 16 + m15) * 32 + q4 * 8];
#pragma unroll
        for (int j = 0; j < 4; ++j)
            bfr[j] = *(const bf16x8*)&S[cur][1][(wn * 64 + j * 16 + m15) * 32 + q4 * 8];
#pragma unroll
        for (int i = 0; i < 4; ++i)
#pragma unroll
            for (int j = 0; j < 4; ++j)
                acc[i][j] = __builtin_amdgcn_mfma_f32_16x16x32_bf16(af[i], bfr[j],
                                                                    acc[i][j], 0, 0, 0);
        __syncthreads();
    }

    if (EPI <= 1) {
        u16* W = &S[0][0][0] + wave * 4096;
#pragma unroll
        for (int jj = 0; jj < 4; ++jj) {
            int n = n0 + wn * 64 + jj * 16 + m15;
            float bv = b2f(bias[n]);
#pragma unroll
            for (int i = 0; i < 4; ++i)
#pragma unroll
                for (int r = 0; r < 4; ++r) {
                    float v = acc[i][jj][r] + bv;
                    if (EPI == 1) v = gelu_f(v);
                    W[(i * 16 + q4 * 4 + r) * 64 + jj * 16 + m15] = f2b_fast(v);
                }
        }
#pragma unroll
        for (int o = 0; o < 8; ++o) {
            int lrow = o * 8 + (lane >> 3);
            int c8 = (lane & 7) * 8;
            uint4 v = *(const uint4*)&W[lrow * 64 + c8];
            *(uint4*)&Cout[(size_t)(m0 + wm * 64 + lrow) * N + n0 + wn * 64 + c8] = v;
        }
    } else {
        constexpr int CSTR = 132;
        float* Cs = (float*)&S[0][0][0];
#pragma unroll
        for (int p = 0; p < 4; ++p) {
            __syncthreads();
            if (wm == (p >> 1)) {
                const int ibase = (p & 1) * 2;
#pragma unroll
                for (int jj = 0; jj < 4; ++jj) {
                    int n = n0 + wn * 64 + jj * 16 + m15;
                    float bv = b2f(bias[n]);
#pragma unroll
                    for (int ii = 0; ii < 2; ++ii) {
                        int i = ibase + ii;
#pragma unroll
                        for (int r = 0; r < 4; ++r) {
                            float v = acc[i][jj][r] + bv;
                            Cs[(ii * 16 + q4 * 4 + r) * CSTR + wn * 64 + jj * 16 + m15] = v;
                        }
                    }
                }
            }
            __syncthreads();
#pragma unroll
            for (int it = 0; it < 2; ++it) {
                int r2 = it * 16 + (tid >> 4);
                int c8 = (tid & 15) * 8;
                size_t goff = (size_t)(m0 + p * 32 + r2) * N + n0 + c8;
                f32x4 v0 = *(const f32x4*)&Cs[r2 * CSTR + c8];
                f32x4 v1 = *(const f32x4*)&Cs[r2 * CSTR + c8 + 4];
                uint4 rv = *(const uint4*)&res[goff];
                const u16* rp = (const u16*)&rv;
                u16 outv[8];
#pragma unroll
                for (int e = 0; e < 4; ++e) {
                    outv[e] = f2b_fast(v0[e] + b2f(rp[e]));
                    outv[4 + e] = f2b_fast(v1[e] + b2f(rp[4 + e]));
                }
                *(uint4*)&Cout[goff] = *(const uint4*)outv;
            }
        }
    }
}

// ---------------------------------------------------------------------------
// Window attention v3: ONE head per block-wave (grid = 2048 windows x 3 head
// groups), swapped QK^T (mfma(K,Q)) so each lane owns a full q-row -> softmax
// is 16 local ops + 2 shfls; P staged via 16 ds_write_b64 (was 64 scalar);
// Ps/Vt XOR-swizzled (bank-conflict-free, T2 involution on both sides).
// Barrier-free waves, private 8 KB LDS regions.
__global__ __launch_bounds__(256, 3)
void attn_win(const u16* __restrict__ qkv, const float* __restrict__ bias_exp,
              u16* __restrict__ outp) {
    __shared__ __align__(16) u16 lds[4][4096];   // 8 KB per wave
    const int tid = threadIdx.x;
    const int wave = tid >> 6, lane = tid & 63;
    const int win = blockIdx.x / 3;
    const int hp = blockIdx.x - win * 3;
    const int h = hp * 4 + wave;
    const int t0p = win * 49;
    u16* Vt = &lds[wave][0];   // region reuse: in-order per-wave DS + fences
    u16* Ps = &lds[wave][0];
    u16* Po = &lds[wave][0];
    const int m15 = lane & 15, q4 = lane >> 4;
    const int rr = lane >> 2, dq = lane & 3;
    const int swz = (m15 & 7) << 3;            // row-XOR swizzle (u16 units)
    const float scale = 0.17677669529663687f;  // 1/sqrt(32)
    const u16* wbase = qkv + (size_t)t0p * 1152;

    // --- Q/K fragments straight from global (rows >=49 clamp to 48) ---
    bf16x8 qf[4], kf[4];
#pragma unroll
    for (int i = 0; i < 4; ++i) {
        int row = i * 16 + m15;
        int rc = row < 49 ? row : 48;
        const u16* g = wbase + (size_t)rc * 1152 + h * 32 + q4 * 8;
        qf[i] = *(const bf16x8*)g;
        kf[i] = *(const bf16x8*)(g + 384);
    }
    // --- V rows -> LDS transpose, XOR-swizzled rows (d = dq*8+ii) ---
#pragma unroll
    for (int p = 0; p < 4; ++p) {
        int n = p * 16 + rr;
        uint4 vv = {0u, 0u, 0u, 0u};
        if (n < 49)
            vv = *(const uint4*)(wbase + (size_t)n * 1152 + 768 + h * 32 + dq * 8);
        const u16* pv = (const u16*)&vv;
#pragma unroll
        for (int ii = 0; ii < 8; ++ii)
            Vt[((dq * 8 + ii) * 64 + n) ^ (ii << 3)] = pv[ii];
    }
    LGKM0_FENCE();   // Vt writes drained before vf reads
    bf16x8 vf[2][2];
#pragma unroll
    for (int j = 0; j < 2; ++j)
#pragma unroll
        for (int kk = 0; kk < 2; ++kk)
            vf[j][kk] = *(const bf16x8*)&Vt[((j * 16 + m15) * 64 + kk * 32 + q4 * 8) ^ swz];
    // --- swapped QK^T: sc[j][i][r] = S[k = j*16+q4*4+r][q = i*16+m15] ---
    f32x4 sc[4][4];
#pragma unroll
    for (int j = 0; j < 4; ++j)
#pragma unroll
        for (int i = 0; i < 4; ++i) {
            sc[j][i] = {0.f, 0.f, 0.f, 0.f};
            sc[j][i] = __builtin_amdgcn_mfma_f32_16x16x32_bf16(kf[j], qf[i],
                                                               sc[j][i], 0, 0, 0);
        }
    // --- scale + bias (f32x4 per (i,j); mask for q>=49 / k>=49 baked) ---
    const float* bx = bias_exp + h * 4096;
#pragma unroll
    for (int i = 0; i < 4; ++i) {
        int qrow = i * 16 + m15;
#pragma unroll
        for (int j = 0; j < 4; ++j) {
            f32x4 b4 = *(const f32x4*)&bx[qrow * 64 + j * 16 + q4 * 4];
#pragma unroll
            for (int r = 0; r < 4; ++r)
                sc[j][i][r] = fmaf(sc[j][i][r], scale, b4[r]);
        }
    }
    // --- softmax: q-row is lane-local over 16 regs; cross-part = 2 shfls ---
#pragma unroll
    for (int i = 0; i < 4; ++i) {
        float mx = sc[0][i][0];
#pragma unroll
        for (int j = 0; j < 4; ++j)
#pragma unroll
            for (int r = 0; r < 4; ++r) mx = fmaxf(mx, sc[j][i][r]);
        mx = fmaxf(mx, __shfl_xor(mx, 16));
        mx = fmaxf(mx, __shfl_xor(mx, 32));
        float sum = 0.f;
#pragma unroll
        for (int j = 0; j < 4; ++j)
#pragma unroll
            for (int r = 0; r < 4; ++r) {
                float e = __expf(sc[j][i][r] - mx);
                sc[j][i][r] = e;
                sum += e;
            }
        sum += __shfl_xor(sum, 16);
        sum += __shfl_xor(sum, 32);
        float inv = 1.0f / sum;
#pragma unroll
        for (int j = 0; j < 4; ++j)
#pragma unroll
            for (int r = 0; r < 4; ++r) sc[j][i][r] *= inv;
    }
    // --- P -> LDS: 16 x ds_write_b64 (4 consecutive cols/lane), swizzled ---
#pragma unroll
    for (int i = 0; i < 4; ++i)
#pragma unroll
        for (int j = 0; j < 4; ++j) {
            unsigned lo = (unsigned)f2b_fast(sc[j][i][0]) |
                          ((unsigned)f2b_fast(sc[j][i][1]) << 16);
            unsigned hi = (unsigned)f2b_fast(sc[j][i][2]) |
                          ((unsigned)f2b_fast(sc[j][i][3]) << 16);
            uint2 w; w.x = lo; w.y = hi;
            *(uint2*)&Ps[((i * 16 + m15) * 64 + j * 16 + q4 * 4) ^ swz] = w;
        }
    LGKM0_FENCE();   // P writes drained before pf reads
    // --- PV ---
    f32x4 oacc[4][2];
#pragma unroll
    for (int i = 0; i < 4; ++i)
#pragma unroll
        for (int j = 0; j < 2; ++j) oacc[i][j] = {0.f, 0.f, 0.f, 0.f};
#pragma unroll
    for (int i = 0; i < 4; ++i) {
#pragma unroll
        for (int kk = 0; kk < 2; ++kk) {
            bf16x8 pf = *(const bf16x8*)&Ps[((i * 16 + m15) * 64 + kk * 32 + q4 * 8) ^ swz];
#pragma unroll
            for (int j = 0; j < 2; ++j)
                oacc[i][j] = __builtin_amdgcn_mfma_f32_16x16x32_bf16(pf, vf[j][kk],
                                                                     oacc[i][j], 0, 0, 0);
        }
    }
    // --- stage output tile (49x32) in LDS, stride 40 u16 (80B) ---
#pragma unroll
    for (int i = 0; i < 4; ++i)
#pragma unroll
        for (int r = 0; r < 4; ++r) {
            int row = i * 16 + q4 * 4 + r;
#pragma unroll
            for (int j = 0; j < 2; ++j)
                Po[row * 40 + j * 16 + m15] = f2b_fast(oacc[i][j][r]);
        }
    LGKM0_FENCE();   // Po writes drained before coalesced read-out
    // --- full-line coalesced store: 4 lanes x 16B = 64B per row ---
#pragma unroll
    for (int w2 = 0; w2 < 4; ++w2) {
        int row = w2 * 16 + rr;
        if (row < 49) {
            uint4 ov = *(const uint4*)&Po[row * 40 + dq * 8];
            *(uint4*)&outp[(size_t)(t0p + row) * 384 + h * 32 + dq * 8] = ov;
        }
    }
}

// ---------------------------------------------------------------------------
// LN2: y(T,384) bf16 -> out(T,384) bf16. One wave per token, 12B/lane.
__global__ void ln2_kernel(const u16* __restrict__ y, const u16* __restrict__ g2,
                           const u16* __restrict__ b2, u16* __restrict__ out) {
    int wave = threadIdx.x >> 6, lane = threadIdx.x & 63;
    size_t t = (size_t)blockIdx.x * 4 + wave;
    uint3 rv = *(const uint3*)(y + t * 384 + lane * 6);
    float v[6];
    v[0] = b2f((u16)(rv.x & 0xffff)); v[1] = b2f((u16)(rv.x >> 16));
    v[2] = b2f((u16)(rv.y & 0xffff)); v[3] = b2f((u16)(rv.y >> 16));
    v[4] = b2f((u16)(rv.z & 0xffff)); v[5] = b2f((u16)(rv.z >> 16));
    float s = 0.f, sq = 0.f;
#pragma unroll
    for (int i = 0; i < 6; ++i) { s += v[i]; sq += v[i] * v[i]; }
#pragma unroll
    for (int m = 1; m < 64; m <<= 1) {
        s += __shfl_xor(s, m);
        sq += __shfl_xor(sq, m);
    }
    float mean = s * (1.0f / 384.0f);
    float var = sq * (1.0f / 384.0f) - mean * mean;
    float rstd = rsqrtf(var + 1e-5f);
    uint3 gv = *(const uint3*)(g2 + lane * 6);
    uint3 bv = *(const uint3*)(b2 + lane * 6);
    float g[6], bb[6];
    g[0] = b2f((u16)(gv.x & 0xffff)); g[1] = b2f((u16)(gv.x >> 16));
    g[2] = b2f((u16)(gv.y & 0xffff)); g[3] = b2f((u16)(gv.y >> 16));
    g[4] = b2f((u16)(gv.z & 0xffff)); g[5] = b2f((u16)(gv.z >> 16));
    bb[0] = b2f((u16)(bv.x & 0xffff)); bb[1] = b2f((u16)(bv.x >> 16));
    bb[2] = b2f((u16)(bv.y & 0xffff)); bb[3] = b2f((u16)(bv.y >> 16));
    bb[4] = b2f((u16)(bv.z & 0xffff)); bb[5] = b2f((u16)(bv.z >> 16));
    u16 o[6];
#pragma unroll
    for (int i = 0; i < 6; ++i)
        o[i] = f2b_fast((v[i] - mean) * rstd * g[i] + bb[i]);
    uint3 ov;
    ov.x = (unsigned)o[0] | ((unsigned)o[1] << 16);
    ov.y = (unsigned)o[2] | ((unsigned)o[3] << 16);
    ov.z = (unsigned)o[4] | ((unsigned)o[5] << 16);
    *(uint3*)(out + t * 384 + lane * 6) = ov;
}

// ---------------------------------------------------------------------------
// final (T',384) bf16 (window-gathered rows) -> out (B,384,112,112).
// grid (196,6,8), block 256.
__global__ void out_transpose(const u16* __restrict__ fin, void* __restrict__ out,
                              const int* __restrict__ flagp) {
    __shared__ float tile[64][65];
    int isf = flagp[0];
    int hw0 = blockIdx.x * 64, c0 = blockIdx.y * 64, b = blockIdx.z;
    int tid = threadIdx.x;
    {
        int cl = tid & 63, hq = tid >> 6;
#pragma unroll
        for (int it = 0; it < 16; ++it) {
            int hl = hq * 16 + it;
            int tp = tprime(b, hw0 + hl);
            tile[hl][cl] = b2f(fin[(size_t)tp * 384 + c0 + cl]);
        }
    }
    __syncthreads();
    {
        int hl = tid & 63, cq = tid >> 6;
#pragma unroll
        for (int it = 0; it < 16; ++it) {
            int cl = cq * 16 + it;
            size_t o = ((size_t)b * 384 + c0 + cl) * 12544 + hw0 + hl;
            float v = tile[hl][cl];
            if (isf) ((float*)out)[o] = v;
            else     ((u16*)out)[o] = f2b(v);
        }
    }
}

// ---------------------------------------------------------------------------
extern "C" void kernel_launch(void* const* d_in, const int* in_sizes, int n_in,
                              void* d_out, int out_size, void* d_ws, size_t ws_size,
                              hipStream_t stream) {
    constexpr int T = 100352, C = 384, HID = 1536, NQ = 1152;
    const void* x = d_in[0];

    char* ws = (char*)d_ws;
    size_t off = 0;
    auto alloc = [&](size_t bytes) { char* p = ws + off; off += (bytes + 255) & ~(size_t)255; return p; };
    int* flag = (int*)alloc(4);
    // bf16 bias/param vectors
    u16* cb_qkv  = (u16*)alloc((size_t)NQ * 2);
    u16* cb_proj = (u16*)alloc((size_t)C * 2);
    u16* cg1     = (u16*)alloc((size_t)C * 2);
    u16* cb1     = (u16*)alloc((size_t)C * 2);
    u16* cg2     = (u16*)alloc((size_t)C * 2);
    u16* cb2     = (u16*)alloc((size_t)C * 2);
    u16* cb_fc1  = (u16*)alloc((size_t)HID * 2);
    u16* cb_fc2  = (u16*)alloc((size_t)C * 2);
    // transposed bf16 weights (built straight from original dtype)
    u16* wqkvT  = (u16*)alloc((size_t)C * NQ * 2);
    u16* wprojT = (u16*)alloc((size_t)C * C * 2);
    u16* wfc1T  = (u16*)alloc((size_t)C * HID * 2);
    u16* wfc2T  = (u16*)alloc((size_t)HID * C * 2);
    // expanded bias table
    float* biasx = (float*)alloc((size_t)12 * 64 * 64 * 4);
    // activations (token-major, window-gathered t' order)
    u16* xt   = (u16*)alloc((size_t)T * C * 2);
    u16* bufB = (u16*)alloc((size_t)T * C * 2);    // xn -> attnout -> h_in -> final
    u16* bufC = (u16*)alloc((size_t)T * HID * 2);  // qkv -> hid
    u16* ybuf = (u16*)alloc((size_t)T * C * 2);

    // 1) detect input dtype from x
    detect_dtype<<<1, 256, 0, stream>>>((const unsigned int*)x, flag);

    // 2) fused prep: small tensors + bias table; weight transposes
    prep_small<<<1, 256, 0, stream>>>(d_in[1], d_in[2], d_in[4], d_in[7], d_in[8],
                                      d_in[9], d_in[11], d_in[13], d_in[5],
                                      cg1, cb1, cb_qkv, cb_proj, cg2, cb2,
                                      cb_fc1, cb_fc2, biasx, flag);
    prep_w<<<dim3(48, 48, 4), 256, 0, stream>>>(d_in[3], d_in[6], d_in[10], d_in[12],
                                                wqkvT, wprojT, wfc1T, wfc2T, flag);

    // 3) fused LN1 (stats + normalize + transpose, single x pass)
    ln1_fused<<<dim3(196, 8), 256, 0, stream>>>(x, cg1, cb1, xt, bufB, flag);

    // 4) QKV
    gemm_bt<0, NQ, C><<<dim3(NQ / 128, T / 128), 256, 0, stream>>>(
        bufB, wqkvT, cb_qkv, nullptr, bufC, T);
    // 5) attention: 2048 windows x 3 head-groups, one head per wave
    attn_win<<<6144, 256, 0, stream>>>(bufC, biasx, bufB);

    // 6) proj + residual(xt) -> y
    gemm_bt<2, C, C><<<dim3(C / 128, T / 128), 256, 0, stream>>>(
        bufB, wprojT, cb_proj, xt, ybuf, T);
    // 7) LN2 -> bufB
    ln2_kernel<<<T / 4, 256, 0, stream>>>(ybuf, cg2, cb2, bufB);

    // 8) FC1 + gelu -> hid (bufC)
    gemm_bt<1, HID, C><<<dim3(HID / 128, T / 128), 256, 0, stream>>>(
        bufB, wfc1T, cb_fc1, nullptr, bufC, T);
    // 9) FC2 + residual(y) -> final (bufB)
    gemm_bt<2, C, HID><<<dim3(C / 128, T / 128), 256, 0, stream>>>(
        bufC, wfc2T, cb_fc2, ybuf, bufB, T);
    // 10) final transpose to NCHW (dtype per flag)
    out_transpose<<<dim3(196, 6, 8), 256, 0, stream>>>(bufB, d_out, flag);
}